// Round 1
// baseline (2789.296 us; speedup 1.0000x reference)
//
#include <hip/hip_runtime.h>
#include <hip/hip_bf16.h>
#include <math.h>

// Problem constants
#define Bc   2
#define Nc   512
#define Hc   12
#define DHc  64
#define DIMc 768
#define DPAIRc 128
#define DCONDc 512
#define INNERc 3072
#define NQc  32
#define NKc  128
#define NWc  (Nc / NQc)   // 16

// ---------------- helpers ----------------
__device__ inline float wave_sum(float v) {
#pragma unroll
  for (int off = 32; off > 0; off >>= 1) v += __shfl_xor(v, off, 64);
  return v;
}
__device__ inline float wave_max(float v) {
#pragma unroll
  for (int off = 32; off > 0; off >>= 1) v = fmaxf(v, __shfl_xor(v, off, 64));
  return v;
}
// block of 256 threads
__device__ inline float block_sum(float v, float* red) {
  v = wave_sum(v);
  int wv = threadIdx.x >> 6, lane = threadIdx.x & 63;
  __syncthreads();
  if (lane == 0) red[wv] = v;
  __syncthreads();
  return red[0] + red[1] + red[2] + red[3];
}
__device__ inline float sigmoidf(float x) { return 1.0f / (1.0f + expf(-x)); }

// ---------------- LN over rows (cond) ----------------
__global__ __launch_bounds__(256) void ln_rows_k(const float* __restrict__ in,
                                                 float* __restrict__ out, int C) {
  __shared__ float red[4];
  int row = blockIdx.x;
  const float* x = in + (size_t)row * C;
  float s = 0.f;
  for (int c = threadIdx.x; c < C; c += 256) s += x[c];
  float mean = block_sum(s, red) / C;
  float vs = 0.f;
  for (int c = threadIdx.x; c < C; c += 256) { float d = x[c] - mean; vs += d * d; }
  float var = block_sum(vs, red) / C;
  float r = rsqrtf(var + 1e-5f);
  for (int c = threadIdx.x; c < C; c += 256)
    out[(size_t)row * C + c] = (x[c] - mean) * r;
}

// ---------------- generic f32 GEMM with fused epilogue ----------------
#define BM 64
#define BN 64
#define BKt 16
__global__ __launch_bounds__(256) void gemm_f32_k(
    const float* __restrict__ A, const float* __restrict__ Bm, float* __restrict__ C,
    int M, int N, int K,
    const float* __restrict__ bias, int act,
    const float* __restrict__ scale, const float* __restrict__ resid,
    const float* __restrict__ maskp) {
  __shared__ float As[BKt][BM + 1];
  __shared__ float Bs[BKt][BN + 1];
  int t = threadIdx.x;
  int tx = t & 15, ty = t >> 4;
  int m0 = blockIdx.y * BM, n0 = blockIdx.x * BN;
  float acc[4][4] = {};
  for (int k0 = 0; k0 < K; k0 += BKt) {
    for (int e = t; e < BM * BKt; e += 256) {
      int r = e >> 4, c = e & 15;
      As[c][r] = A[(size_t)(m0 + r) * K + k0 + c];
    }
    for (int e = t; e < BKt * BN; e += 256) {
      int r = e >> 6, c = e & 63;
      Bs[r][c] = Bm[(size_t)(k0 + r) * N + n0 + c];
    }
    __syncthreads();
#pragma unroll
    for (int k = 0; k < BKt; ++k) {
      float a[4], b[4];
#pragma unroll
      for (int i = 0; i < 4; ++i) a[i] = As[k][ty * 4 + i];
#pragma unroll
      for (int j = 0; j < 4; ++j) b[j] = Bs[k][tx * 4 + j];
#pragma unroll
      for (int i = 0; i < 4; ++i)
#pragma unroll
        for (int j = 0; j < 4; ++j) acc[i][j] += a[i] * b[j];
    }
    __syncthreads();
  }
#pragma unroll
  for (int i = 0; i < 4; ++i) {
    int m = m0 + ty * 4 + i;
    float mk = maskp ? maskp[m] : 1.0f;
#pragma unroll
    for (int j = 0; j < 4; ++j) {
      int n = n0 + tx * 4 + j;
      float v = acc[i][j];
      if (bias) v += bias[n];
      if (act == 1) v = sigmoidf(v);
      if (scale) v *= scale[(size_t)m * N + n];
      if (resid) v += resid[(size_t)m * N + n];
      if (maskp) v *= mk;
      C[(size_t)m * N + n] = v;
    }
  }
}

// ---------------- adaLN apply ----------------
__global__ __launch_bounds__(256) void adaln_apply_k(
    const float* __restrict__ xin, const float* __restrict__ maskp,
    const float* __restrict__ g, const float* __restrict__ bv,
    float* __restrict__ xa, float* __restrict__ xm, int C) {
  __shared__ float red[4];
  int row = blockIdx.x;
  float mk = maskp[row];
  const float* xr = xin + (size_t)row * C;
  float vals[3];
  int nIt = (C + 255) >> 8;  // C=768 -> 3
  float s = 0.f;
  for (int it = 0; it < nIt; ++it) {
    int c = threadIdx.x + it * 256;
    float v = (c < C) ? xr[c] * mk : 0.f;
    vals[it] = v;
    s += v;
  }
  float mean = block_sum(s, red) / C;
  float vs = 0.f;
  for (int it = 0; it < nIt; ++it) {
    int c = threadIdx.x + it * 256;
    if (c < C) { float d = vals[it] - mean; vs += d * d; }
  }
  float var = block_sum(vs, red) / C;
  float r = rsqrtf(var + 1e-5f);
  for (int it = 0; it < nIt; ++it) {
    int c = threadIdx.x + it * 256;
    if (c < C) {
      size_t idx = (size_t)row * C + c;
      if (xm) xm[idx] = vals[it];
      xa[idx] = ((vals[it] - mean) * r * g[idx] + bv[idx]) * mk;
    }
  }
}

// ---------------- per-head LN + RoPE (in place), wave per (b,n,h) ----------------
__global__ __launch_bounds__(256) void lnrope_k(float* __restrict__ q) {
  int rowid = blockIdx.x * 4 + (threadIdx.x >> 6);  // (b*Nc+n)*Hc + h
  int lane = threadIdx.x & 63;
  int bn = rowid / Hc;
  int h = rowid - bn * Hc;
  int n = bn & (Nc - 1);
  size_t base = (size_t)bn * (Hc * DHc) + h * DHc;
  float v = q[base + lane];
  float mean = wave_sum(v) * (1.0f / 64.0f);
  float d = v - mean;
  float var = wave_sum(d * d) * (1.0f / 64.0f);
  float vn = d * rsqrtf(var + 1e-5f);
  int i = lane >> 1;
  float inv = powf(10000.0f, -(float)(2 * i) / 64.0f);
  float ang = (float)n * inv;
  float c = cosf(ang), s = sinf(ang);
  float partner = __shfl_xor(vn, 1, 64);
  float out = (lane & 1) ? (partner * s + vn * c) : (vn * c - partner * s);
  q[base + lane] = out;
}

// ---------------- windowed pair bias ----------------
__global__ __launch_bounds__(256) void pair_bias_k(
    const float* __restrict__ pr, const float* __restrict__ wb,
    float* __restrict__ biasw) {
  int task = blockIdx.x * 4 + (threadIdx.x >> 6);  // (b*Nc + i)*NKc + k
  int lane = threadIdx.x & 63;
  int k = task & (NKc - 1);
  int bi = task >> 7;
  int i = bi & (Nc - 1);
  int b = bi >> 9;
  int w = i >> 5, qi = i & 31;
  int j = w * NQc - 48 + k;
  int jc = min(max(j, 0), Nc - 1);
  const float* row = pr + (((size_t)(b * Nc + i)) * Nc + jc) * DPAIRc;
  float e0 = row[lane], e1 = row[lane + 64];
  float mean = wave_sum(e0 + e1) * (1.0f / 128.0f);
  float d0 = e0 - mean, d1 = e1 - mean;
  float var = wave_sum(d0 * d0 + d1 * d1) * (1.0f / 128.0f);
  float r = rsqrtf(var + 1e-5f);
  d0 *= r; d1 *= r;
#pragma unroll
  for (int h = 0; h < Hc; ++h) {
    float p = d0 * wb[lane * Hc + h] + d1 * wb[(lane + 64) * Hc + h];
    p = wave_sum(p);
    if (lane == 0)
      biasw[((((size_t)(b * Hc + h)) * NWc + w) * NQc + qi) * NKc + k] = p;
  }
}

// ---------------- windowed attention ----------------
__global__ __launch_bounds__(256) void wattn_k(
    const float* __restrict__ q, const float* __restrict__ kbuf,
    const float* __restrict__ vbuf, const float* __restrict__ biasw,
    const float* __restrict__ pair_mask, float* __restrict__ o) {
  __shared__ float qs[32][65];
  __shared__ float ks[128][65];
  __shared__ float vs[128][65];
  __shared__ float sc[32][129];
  int blk = blockIdx.x;  // (b*Hc + h)*NWc + w
  int w = blk & (NWc - 1);
  int bh = blk >> 4;
  int h = bh % Hc;
  int b = bh / Hc;
  int t = threadIdx.x;
  for (int e = t; e < 32 * 64; e += 256) {
    int qi = e >> 6, d = e & 63;
    qs[qi][d] = q[((size_t)(b * Nc + w * NQc + qi)) * (Hc * DHc) + h * DHc + d];
  }
  for (int e = t; e < 128 * 64; e += 256) {
    int kk = e >> 6, d = e & 63;
    int j = w * NQc - 48 + kk;
    int jc = min(max(j, 0), Nc - 1);
    size_t src = ((size_t)(b * Nc + jc)) * (Hc * DHc) + h * DHc + d;
    ks[kk][d] = kbuf[src];
    vs[kk][d] = vbuf[src];
  }
  __syncthreads();
  int qi = t >> 3;
  int kbase = (t & 7) * 16;
  const float* bwp = biasw + (((size_t)blk) * NQc + qi) * NKc;
#pragma unroll
  for (int e = 0; e < 16; ++e) {
    int kk = kbase + e;
    float acc = 0.f;
#pragma unroll
    for (int d = 0; d < 64; ++d) acc += qs[qi][d] * ks[kk][d];
    int j = w * NQc - 48 + kk;
    bool valid = (j >= 0) && (j < Nc);
    int jc = min(max(j, 0), Nc - 1);
    float pm = pair_mask[((size_t)(b * Nc + w * NQc + qi)) * Nc + jc];
    bool ok = valid && (pm > 0.f);
    float sv = acc * 0.125f + bwp[kk];
    sc[qi][kk] = ok ? sv : -1e9f;
  }
  __syncthreads();
  int lane = t & 63, wv = t >> 6;
#pragma unroll
  for (int rr = 0; rr < 8; ++rr) {
    int qq = wv * 8 + rr;
    float v0 = sc[qq][lane], v1 = sc[qq][lane + 64];
    float mx = wave_max(fmaxf(v0, v1));
    float e0 = expf(v0 - mx), e1 = expf(v1 - mx);
    float inv = 1.0f / wave_sum(e0 + e1);
    sc[qq][lane] = e0 * inv;
    sc[qq][lane + 64] = e1 * inv;
  }
  __syncthreads();
  int dbase = (t & 7) * 8;
  float accv[8] = {};
  for (int kk = 0; kk < 128; ++kk) {
    float a = sc[qi][kk];
#pragma unroll
    for (int d2 = 0; d2 < 8; ++d2) accv[d2] += a * vs[kk][dbase + d2];
  }
  size_t obase = ((size_t)(b * Nc + w * NQc + qi)) * (Hc * DHc) + h * DHc + dbase;
#pragma unroll
  for (int d2 = 0; d2 < 8; ++d2) o[obase + d2] = accv[d2];
}

// ---------------- elementwise kernels ----------------
__global__ __launch_bounds__(256) void gate_k(float* __restrict__ o,
                                              const float* __restrict__ g, int n) {
  int i = blockIdx.x * 256 + threadIdx.x;
  if (i < n) o[i] = o[i] * sigmoidf(g[i]);
}

__global__ __launch_bounds__(256) void silu_gate_k(const float* __restrict__ h,
                                                   float* __restrict__ act, int total) {
  int i = blockIdx.x * 256 + threadIdx.x;
  if (i < total) {
    int m = i / INNERc, j = i - m * INNERc;
    float a = h[(size_t)m * (2 * INNERc) + j];
    float g = h[(size_t)m * (2 * INNERc) + INNERc + j];
    act[i] = a * g * sigmoidf(g);
  }
}

extern "C" void kernel_launch(void* const* d_in, const int* in_sizes, int n_in,
                              void* d_out, int out_size, void* d_ws, size_t ws_size,
                              hipStream_t stream) {
  const float* x        = (const float*)d_in[0];
  const float* pair_rep = (const float*)d_in[1];
  const float* cond     = (const float*)d_in[2];
  const float* mask     = (const float*)d_in[3];
  const float* pair_mask= (const float*)d_in[4];
  const float* a1_gw    = (const float*)d_in[5];
  const float* a1_gb    = (const float*)d_in[6];
  const float* a1_bw    = (const float*)d_in[7];
  const float* wq       = (const float*)d_in[8];
  const float* bq       = (const float*)d_in[9];
  const float* wk       = (const float*)d_in[10];
  const float* bk       = (const float*)d_in[11];
  const float* wv       = (const float*)d_in[12];
  const float* bv       = (const float*)d_in[13];
  const float* wg       = (const float*)d_in[14];
  const float* bg       = (const float*)d_in[15];
  const float* wb_pair  = (const float*)d_in[16];
  const float* wo       = (const float*)d_in[17];
  const float* bo       = (const float*)d_in[18];
  const float* s1_w     = (const float*)d_in[19];
  const float* s1_b     = (const float*)d_in[20];
  const float* a2_gw    = (const float*)d_in[21];
  const float* a2_gb    = (const float*)d_in[22];
  const float* a2_bw    = (const float*)d_in[23];
  const float* tr_win   = (const float*)d_in[24];
  const float* tr_wout  = (const float*)d_in[25];
  const float* s2_w     = (const float*)d_in[26];
  const float* s2_b     = (const float*)d_in[27];
  float* out = (float*)d_out;

  const int M = Bc * Nc;  // 1024
  float* ws = (float*)d_ws;
  size_t off = 0;
  auto alloc = [&](size_t n) { float* p = ws + off; off += n; return p; };
  float* cn    = alloc((size_t)M * DCONDc);
  float* g1    = alloc((size_t)M * DIMc);
  float* b1    = alloc((size_t)M * DIMc);
  float* s1    = alloc((size_t)M * DIMc);
  float* g2    = alloc((size_t)M * DIMc);
  float* b2    = alloc((size_t)M * DIMc);
  float* s2    = alloc((size_t)M * DIMc);
  float* xm    = alloc((size_t)M * DIMc);
  float* xa    = alloc((size_t)M * DIMc);
  float* qb    = alloc((size_t)M * DIMc);
  float* kb    = alloc((size_t)M * DIMc);
  float* vb    = alloc((size_t)M * DIMc);
  float* gb    = alloc((size_t)M * DIMc);
  float* biasw = alloc((size_t)Bc * Hc * NWc * NQc * NKc);
  float* ob    = alloc((size_t)M * DIMc);
  float* x2    = alloc((size_t)M * DIMc);
  float* xt    = alloc((size_t)M * DIMc);
  float* hb    = alloc((size_t)M * 2 * INNERc);
  float* actb  = alloc((size_t)M * INNERc);
  (void)ws_size; (void)in_sizes; (void)n_in; (void)out_size;

  dim3 blk(256);
  dim3 gc(DIMc / BN, M / BM);

  ln_rows_k<<<M, blk, 0, stream>>>(cond, cn, DCONDc);

  gemm_f32_k<<<gc, blk, 0, stream>>>(cn, a1_gw, g1, M, DIMc, DCONDc, a1_gb, 1, nullptr, nullptr, nullptr);
  gemm_f32_k<<<gc, blk, 0, stream>>>(cn, a1_bw, b1, M, DIMc, DCONDc, nullptr, 0, nullptr, nullptr, nullptr);
  gemm_f32_k<<<gc, blk, 0, stream>>>(cn, s1_w,  s1, M, DIMc, DCONDc, s1_b, 1, nullptr, nullptr, nullptr);
  gemm_f32_k<<<gc, blk, 0, stream>>>(cn, a2_gw, g2, M, DIMc, DCONDc, a2_gb, 1, nullptr, nullptr, nullptr);
  gemm_f32_k<<<gc, blk, 0, stream>>>(cn, a2_bw, b2, M, DIMc, DCONDc, nullptr, 0, nullptr, nullptr, nullptr);
  gemm_f32_k<<<gc, blk, 0, stream>>>(cn, s2_w,  s2, M, DIMc, DCONDc, s2_b, 1, nullptr, nullptr, nullptr);

  adaln_apply_k<<<M, blk, 0, stream>>>(x, mask, g1, b1, xa, xm, DIMc);

  gemm_f32_k<<<gc, blk, 0, stream>>>(xa, wq, qb, M, DIMc, DIMc, bq, 0, nullptr, nullptr, nullptr);
  gemm_f32_k<<<gc, blk, 0, stream>>>(xa, wk, kb, M, DIMc, DIMc, bk, 0, nullptr, nullptr, nullptr);
  gemm_f32_k<<<gc, blk, 0, stream>>>(xa, wv, vb, M, DIMc, DIMc, bv, 0, nullptr, nullptr, nullptr);
  gemm_f32_k<<<gc, blk, 0, stream>>>(xa, wg, gb, M, DIMc, DIMc, bg, 0, nullptr, nullptr, nullptr);

  lnrope_k<<<(M * Hc) / 4, blk, 0, stream>>>(qb);
  lnrope_k<<<(M * Hc) / 4, blk, 0, stream>>>(kb);

  pair_bias_k<<<(Bc * Nc * NKc) / 4, blk, 0, stream>>>(pair_rep, wb_pair, biasw);

  wattn_k<<<Bc * Hc * NWc, blk, 0, stream>>>(qb, kb, vb, biasw, pair_mask, ob);

  gate_k<<<(M * DIMc + 255) / 256, blk, 0, stream>>>(ob, gb, M * DIMc);

  gemm_f32_k<<<gc, blk, 0, stream>>>(ob, wo, x2, M, DIMc, DIMc, bo, 0, s1, xm, mask);

  adaln_apply_k<<<M, blk, 0, stream>>>(x2, mask, g2, b2, xt, nullptr, DIMc);

  dim3 gt(2 * INNERc / BN, M / BM);
  gemm_f32_k<<<gt, blk, 0, stream>>>(xt, tr_win, hb, M, 2 * INNERc, DIMc, nullptr, 0, nullptr, nullptr, nullptr);

  silu_gate_k<<<(M * INNERc + 255) / 256, blk, 0, stream>>>(hb, actb, M * INNERc);

  gemm_f32_k<<<gc, blk, 0, stream>>>(actb, tr_wout, out, M, DIMc, INNERc, nullptr, 0, s2, x2, mask);
}

// Round 2
// 980.840 us; speedup vs baseline: 2.8438x; 2.8438x over previous
//
#include <hip/hip_runtime.h>
#include <hip/hip_bf16.h>
#include <math.h>

// Problem constants
#define Bc   2
#define Nc   512
#define Hc   12
#define DHc  64
#define DIMc 768
#define DPAIRc 128
#define DCONDc 512
#define INNERc 3072
#define NQc  32
#define NKc  128
#define NWc  (Nc / NQc)   // 16

typedef __attribute__((ext_vector_type(8))) short short8;
typedef __attribute__((ext_vector_type(4))) float floatx4;

// ---------------- helpers ----------------
__device__ inline float wave_sum(float v) {
#pragma unroll
  for (int off = 32; off > 0; off >>= 1) v += __shfl_xor(v, off, 64);
  return v;
}
__device__ inline float wave_max(float v) {
#pragma unroll
  for (int off = 32; off > 0; off >>= 1) v = fmaxf(v, __shfl_xor(v, off, 64));
  return v;
}
__device__ inline float block_sum(float v, float* red) {
  v = wave_sum(v);
  int wv = threadIdx.x >> 6, lane = threadIdx.x & 63;
  __syncthreads();
  if (lane == 0) red[wv] = v;
  __syncthreads();
  return red[0] + red[1] + red[2] + red[3];
}
__device__ inline float sigmoidf(float x) { return 1.0f / (1.0f + expf(-x)); }

// ---------------- LN over rows of cond -> bf16 ----------------
__global__ __launch_bounds__(256) void ln_rows_bf16_k(const float* __restrict__ in,
                                                      __hip_bfloat16* __restrict__ out, int C) {
  __shared__ float red[4];
  int row = blockIdx.x;
  const float* x = in + (size_t)row * C;
  float s = 0.f;
  for (int c = threadIdx.x; c < C; c += 256) s += x[c];
  float mean = block_sum(s, red) / C;
  float vs = 0.f;
  for (int c = threadIdx.x; c < C; c += 256) { float d = x[c] - mean; vs += d * d; }
  float var = block_sum(vs, red) / C;
  float r = rsqrtf(var + 1e-5f);
  for (int c = threadIdx.x; c < C; c += 256)
    out[(size_t)row * C + c] = __float2bfloat16((x[c] - mean) * r);
}

// ---------------- transpose + cast f32[K,N] -> bf16[N,K] ----------------
__global__ __launch_bounds__(256) void transpose_cast_k(const float* __restrict__ src,
                                                        __hip_bfloat16* __restrict__ dst,
                                                        int K, int N) {
  __shared__ float tile[32][33];
  int k0 = blockIdx.y * 32, n0 = blockIdx.x * 32;
  int t = threadIdx.x;
  int r = t >> 5, c = t & 31;
#pragma unroll
  for (int i = 0; i < 4; ++i) tile[r + i * 8][c] = src[(size_t)(k0 + r + i * 8) * N + n0 + c];
  __syncthreads();
#pragma unroll
  for (int i = 0; i < 4; ++i)
    dst[(size_t)(n0 + r + i * 8) * K + k0 + c] = __float2bfloat16(tile[c][r + i * 8]);
}

// ---------------- concat biases ----------------
__global__ __launch_bounds__(256) void concat_bias_k(
    const float* __restrict__ a1_gb, const float* __restrict__ s1_b,
    const float* __restrict__ a2_gb, const float* __restrict__ s2_b,
    const float* __restrict__ bq, const float* __restrict__ bk,
    const float* __restrict__ bv, const float* __restrict__ bg,
    float* __restrict__ cb6, float* __restrict__ bqkvg) {
  int i = blockIdx.x * 256 + threadIdx.x;
  if (i < 6 * DIMc) {
    int seg = i / DIMc, o = i - seg * DIMc;
    float v = 0.f;
    if (seg == 0) v = a1_gb[o];
    else if (seg == 2) v = s1_b[o];
    else if (seg == 3) v = a2_gb[o];
    else if (seg == 5) v = s2_b[o];
    cb6[i] = v;
  }
  if (i < 4 * DIMc) {
    int seg = i / DIMc, o = i - seg * DIMc;
    bqkvg[i] = (seg == 0) ? bq[o] : (seg == 1) ? bk[o] : (seg == 2) ? bv[o] : bg[o];
  }
}

// ---------------- bf16 MFMA GEMM: C[M,N] = A[M,K] @ Bt[N,K]^T + epilogue -------
// block: 256 thr = 4 waves (2x2), TM=128, TN=32*WNT, wave tile 64 x 16*WNT
// mode 0: +bias. mode 1 (wo): v=(acc+bias)*sig(ss)*mk^2; v=(v+resid)*mk
// mode 2 (final): v=acc*mk*sig(ss)*mk^2; v=(v+resid)*mk^2
template <int WNT>
__global__ __launch_bounds__(256) void gemm_bf16_k(
    const __hip_bfloat16* __restrict__ A, const __hip_bfloat16* __restrict__ Bt,
    float* __restrict__ C, int M, int N, int K,
    const float* __restrict__ bias,
    const float* __restrict__ ss, int ssst,
    const float* __restrict__ resid, const float* __restrict__ maskp, int mode) {
  constexpr int TN = 32 * WNT;
  constexpr int LD = 40;  // padded row (bf16 elems) to break bank conflicts
  __shared__ __hip_bfloat16 As[128 * LD];
  __shared__ __hip_bfloat16 Bs[TN * LD];
  int tid = threadIdx.x;
  int lane = tid & 63, wv = tid >> 6;
  int l16 = lane & 15, quad = lane >> 4;
  int m0 = blockIdx.y * 128, n0 = blockIdx.x * TN;
  int wm0 = (wv >> 1) * 64, wn0 = (wv & 1) * (16 * WNT);

  floatx4 acc[4][WNT];
#pragma unroll
  for (int mi = 0; mi < 4; ++mi)
#pragma unroll
    for (int nj = 0; nj < WNT; ++nj) acc[mi][nj] = (floatx4){0.f, 0.f, 0.f, 0.f};

  for (int k0 = 0; k0 < K; k0 += 32) {
#pragma unroll
    for (int e = tid; e < 512; e += 256) {
      int row = e >> 2, kc = (e & 3) * 8;
      *(uint4*)(void*)&As[row * LD + kc] =
          *(const uint4*)(const void*)&A[(size_t)(m0 + row) * K + k0 + kc];
    }
#pragma unroll
    for (int e = tid; e < TN * 4; e += 256) {
      int row = e >> 2, kc = (e & 3) * 8;
      *(uint4*)(void*)&Bs[row * LD + kc] =
          *(const uint4*)(const void*)&Bt[(size_t)(n0 + row) * K + k0 + kc];
    }
    __syncthreads();
    short8 a[4], b[WNT];
#pragma unroll
    for (int mi = 0; mi < 4; ++mi)
      a[mi] = *(const short8*)(const void*)&As[(wm0 + mi * 16 + l16) * LD + quad * 8];
#pragma unroll
    for (int nj = 0; nj < WNT; ++nj)
      b[nj] = *(const short8*)(const void*)&Bs[(wn0 + nj * 16 + l16) * LD + quad * 8];
#pragma unroll
    for (int mi = 0; mi < 4; ++mi)
#pragma unroll
      for (int nj = 0; nj < WNT; ++nj)
        acc[mi][nj] = __builtin_amdgcn_mfma_f32_16x16x32_bf16(a[mi], b[nj], acc[mi][nj], 0, 0, 0);
    __syncthreads();
  }

#pragma unroll
  for (int mi = 0; mi < 4; ++mi) {
#pragma unroll
    for (int nj = 0; nj < WNT; ++nj) {
      int ncol = n0 + wn0 + nj * 16 + l16;
      float bb = bias ? bias[ncol] : 0.f;
#pragma unroll
      for (int r = 0; r < 4; ++r) {
        int m = m0 + wm0 + mi * 16 + quad * 4 + r;
        float v = acc[mi][nj][r] + bb;
        if (mode == 1) {
          float mk = maskp[m];
          v *= sigmoidf(ss[(size_t)m * ssst + ncol]) * mk * mk;
          v = (v + resid[(size_t)m * N + ncol]) * mk;
        } else if (mode == 2) {
          float mk = maskp[m];
          v = v * mk * sigmoidf(ss[(size_t)m * ssst + ncol]) * mk * mk;
          v = (v + resid[(size_t)m * N + ncol]) * mk * mk;
        }
        C[(size_t)m * N + ncol] = v;
      }
    }
  }
}

// ---------------- adaLN apply (raw proj inputs, sigmoid fused) ----------------
__global__ __launch_bounds__(256) void adaln_apply_k(
    const float* __restrict__ xin, const float* __restrict__ maskp,
    const float* __restrict__ graw, const float* __restrict__ braw, int ssst,
    __hip_bfloat16* __restrict__ xa, float* __restrict__ xm) {
  __shared__ float red[4];
  int row = blockIdx.x;
  float mk = maskp[row];
  const float* xr = xin + (size_t)row * DIMc;
  float vals[3];
  float s = 0.f;
#pragma unroll
  for (int it = 0; it < 3; ++it) {
    int c = threadIdx.x + it * 256;
    float v = xr[c] * mk;
    vals[it] = v;
    s += v;
  }
  float mean = block_sum(s, red) * (1.0f / DIMc);
  float vs = 0.f;
#pragma unroll
  for (int it = 0; it < 3; ++it) { float d = vals[it] - mean; vs += d * d; }
  float var = block_sum(vs, red) * (1.0f / DIMc);
  float r = rsqrtf(var + 1e-5f);
#pragma unroll
  for (int it = 0; it < 3; ++it) {
    int c = threadIdx.x + it * 256;
    size_t sidx = (size_t)row * ssst + c;
    if (xm) xm[(size_t)row * DIMc + c] = vals[it];
    float o = ((vals[it] - mean) * r * sigmoidf(graw[sidx]) + braw[sidx]) * mk;
    xa[(size_t)row * DIMc + c] = __float2bfloat16(o);
  }
}

// ---------------- per-head LN + RoPE (in place, stride 3072) ----------------
__global__ __launch_bounds__(256) void lnrope_k(float* __restrict__ q) {
  int rowid = blockIdx.x * 4 + (threadIdx.x >> 6);  // (b*Nc+n)*Hc + h
  int lane = threadIdx.x & 63;
  int bn = rowid / Hc;
  int h = rowid - bn * Hc;
  int n = bn & (Nc - 1);
  size_t base = (size_t)bn * (4 * DIMc) + h * DHc;
  float v = q[base + lane];
  float mean = wave_sum(v) * (1.0f / 64.0f);
  float d = v - mean;
  float var = wave_sum(d * d) * (1.0f / 64.0f);
  float vn = d * rsqrtf(var + 1e-5f);
  int i = lane >> 1;
  float inv = powf(10000.0f, -(float)(2 * i) / 64.0f);
  float ang = (float)n * inv;
  float c = cosf(ang), s = sinf(ang);
  float partner = __shfl_xor(vn, 1, 64);
  float out = (lane & 1) ? (partner * s + vn * c) : (vn * c - partner * s);
  q[base + lane] = out;
}

// ---------------- windowed pair bias ----------------
__global__ __launch_bounds__(256) void pair_bias_k(
    const float* __restrict__ pr, const float* __restrict__ wb,
    float* __restrict__ biasw) {
  int task = blockIdx.x * 4 + (threadIdx.x >> 6);  // (b*Nc + i)*NKc + k
  int lane = threadIdx.x & 63;
  int k = task & (NKc - 1);
  int bi = task >> 7;
  int i = bi & (Nc - 1);
  int b = bi >> 9;
  int w = i >> 5, qi = i & 31;
  int j = w * NQc - 48 + k;
  int jc = min(max(j, 0), Nc - 1);
  const float* row = pr + (((size_t)(b * Nc + i)) * Nc + jc) * DPAIRc;
  float e0 = row[lane], e1 = row[lane + 64];
  float mean = wave_sum(e0 + e1) * (1.0f / 128.0f);
  float d0 = e0 - mean, d1 = e1 - mean;
  float var = wave_sum(d0 * d0 + d1 * d1) * (1.0f / 128.0f);
  float r = rsqrtf(var + 1e-5f);
  d0 *= r; d1 *= r;
#pragma unroll
  for (int h = 0; h < Hc; ++h) {
    float p = d0 * wb[lane * Hc + h] + d1 * wb[(lane + 64) * Hc + h];
    p = wave_sum(p);
    if (lane == 0)
      biasw[((((size_t)(b * Hc + h)) * NWc + w) * NQc + qi) * NKc + k] = p;
  }
}

// ---------------- windowed attention (packed QKVG, fused output gate) --------
__global__ __launch_bounds__(256) void wattn_k(
    const float* __restrict__ qkvg, const float* __restrict__ biasw,
    const float* __restrict__ pair_mask, __hip_bfloat16* __restrict__ o) {
  __shared__ float qs[32][65];
  __shared__ float ks[128][65];
  __shared__ float vs[128][65];
  __shared__ float sc[32][129];
  const int QS = 4 * DIMc;  // 3072
  int blk = blockIdx.x;  // (b*Hc + h)*NWc + w
  int w = blk & (NWc - 1);
  int bh = blk >> 4;
  int h = bh % Hc;
  int b = bh / Hc;
  int t = threadIdx.x;
  for (int e = t; e < 32 * 64; e += 256) {
    int qi = e >> 6, d = e & 63;
    qs[qi][d] = qkvg[(size_t)(b * Nc + w * NQc + qi) * QS + h * DHc + d];
  }
  for (int e = t; e < 128 * 64; e += 256) {
    int kk = e >> 6, d = e & 63;
    int j = w * NQc - 48 + kk;
    int jc = min(max(j, 0), Nc - 1);
    size_t src = (size_t)(b * Nc + jc) * QS + h * DHc + d;
    ks[kk][d] = qkvg[src + DIMc];
    vs[kk][d] = qkvg[src + 2 * DIMc];
  }
  __syncthreads();
  int qi = t >> 3;
  int kbase = (t & 7) * 16;
  const float* bwp = biasw + (((size_t)blk) * NQc + qi) * NKc;
#pragma unroll
  for (int e = 0; e < 16; ++e) {
    int kk = kbase + e;
    float acc = 0.f;
#pragma unroll
    for (int d = 0; d < 64; ++d) acc += qs[qi][d] * ks[kk][d];
    int j = w * NQc - 48 + kk;
    bool valid = (j >= 0) && (j < Nc);
    int jc = min(max(j, 0), Nc - 1);
    float pm = pair_mask[((size_t)(b * Nc + w * NQc + qi)) * Nc + jc];
    bool ok = valid && (pm > 0.f);
    float sv = acc * 0.125f + bwp[kk];
    sc[qi][kk] = ok ? sv : -1e9f;
  }
  __syncthreads();
  int lane = t & 63, wv = t >> 6;
#pragma unroll
  for (int rr = 0; rr < 8; ++rr) {
    int qq = wv * 8 + rr;
    float v0 = sc[qq][lane], v1 = sc[qq][lane + 64];
    float mx = wave_max(fmaxf(v0, v1));
    float e0 = expf(v0 - mx), e1 = expf(v1 - mx);
    float inv = 1.0f / wave_sum(e0 + e1);
    sc[qq][lane] = e0 * inv;
    sc[qq][lane + 64] = e1 * inv;
  }
  __syncthreads();
  int dbase = (t & 7) * 8;
  float accv[8] = {};
  for (int kk = 0; kk < 128; ++kk) {
    float a = sc[qi][kk];
#pragma unroll
    for (int d2 = 0; d2 < 8; ++d2) accv[d2] += a * vs[kk][dbase + d2];
  }
  size_t mrow = (size_t)(b * Nc + w * NQc + qi);
#pragma unroll
  for (int d2 = 0; d2 < 8; ++d2) {
    float g = qkvg[mrow * QS + 3 * DIMc + h * DHc + dbase + d2];
    o[mrow * DIMc + h * DHc + dbase + d2] = __float2bfloat16(accv[d2] * sigmoidf(g));
  }
}

// ---------------- silu gate -> bf16 ----------------
__global__ __launch_bounds__(256) void silu_gate_k(const float* __restrict__ h,
                                                   __hip_bfloat16* __restrict__ act, int total) {
  int i = blockIdx.x * 256 + threadIdx.x;
  if (i < total) {
    int m = i / INNERc, j = i - m * INNERc;
    float a = h[(size_t)m * (2 * INNERc) + j];
    float g = h[(size_t)m * (2 * INNERc) + INNERc + j];
    act[i] = __float2bfloat16(a * g * sigmoidf(g));
  }
}

extern "C" void kernel_launch(void* const* d_in, const int* in_sizes, int n_in,
                              void* d_out, int out_size, void* d_ws, size_t ws_size,
                              hipStream_t stream) {
  const float* x        = (const float*)d_in[0];
  const float* pair_rep = (const float*)d_in[1];
  const float* cond     = (const float*)d_in[2];
  const float* mask     = (const float*)d_in[3];
  const float* pair_mask= (const float*)d_in[4];
  const float* a1_gw    = (const float*)d_in[5];
  const float* a1_gb    = (const float*)d_in[6];
  const float* a1_bw    = (const float*)d_in[7];
  const float* wq       = (const float*)d_in[8];
  const float* bq       = (const float*)d_in[9];
  const float* wk       = (const float*)d_in[10];
  const float* bk       = (const float*)d_in[11];
  const float* wv       = (const float*)d_in[12];
  const float* bv       = (const float*)d_in[13];
  const float* wg       = (const float*)d_in[14];
  const float* bg       = (const float*)d_in[15];
  const float* wb_pair  = (const float*)d_in[16];
  const float* wo       = (const float*)d_in[17];
  const float* bo       = (const float*)d_in[18];
  const float* s1_w     = (const float*)d_in[19];
  const float* s1_b     = (const float*)d_in[20];
  const float* a2_gw    = (const float*)d_in[21];
  const float* a2_gb    = (const float*)d_in[22];
  const float* a2_bw    = (const float*)d_in[23];
  const float* tr_win   = (const float*)d_in[24];
  const float* tr_wout  = (const float*)d_in[25];
  const float* s2_w     = (const float*)d_in[26];
  const float* s2_b     = (const float*)d_in[27];
  float* out = (float*)d_out;

  const int M = Bc * Nc;  // 1024
  char* wsb = (char*)d_ws;
  size_t off = 0;
  auto alloc = [&](size_t bytes) { void* p = wsb + off; off += (bytes + 255) & ~(size_t)255; return p; };

  __hip_bfloat16* cnb    = (__hip_bfloat16*)alloc((size_t)M * DCONDc * 2);
  __hip_bfloat16* Wc6t   = (__hip_bfloat16*)alloc((size_t)6 * DIMc * DCONDc * 2);
  __hip_bfloat16* Wqkvgt = (__hip_bfloat16*)alloc((size_t)4 * DIMc * DIMc * 2);
  __hip_bfloat16* wot    = (__hip_bfloat16*)alloc((size_t)DIMc * DIMc * 2);
  __hip_bfloat16* twint  = (__hip_bfloat16*)alloc((size_t)2 * INNERc * DIMc * 2);
  __hip_bfloat16* twoutt = (__hip_bfloat16*)alloc((size_t)DIMc * INNERc * 2);
  float* cb6   = (float*)alloc((size_t)6 * DIMc * 4);
  float* bqkvg = (float*)alloc((size_t)4 * DIMc * 4);
  float* proj_c= (float*)alloc((size_t)M * 6 * DIMc * 4);
  float* xm    = (float*)alloc((size_t)M * DIMc * 4);
  __hip_bfloat16* xa  = (__hip_bfloat16*)alloc((size_t)M * DIMc * 2);
  float* qkvg  = (float*)alloc((size_t)M * 4 * DIMc * 4);
  float* biasw = (float*)alloc((size_t)Bc * Hc * NWc * NQc * NKc * 4);
  __hip_bfloat16* obg = (__hip_bfloat16*)alloc((size_t)M * DIMc * 2);
  float* x2    = (float*)alloc((size_t)M * DIMc * 4);
  __hip_bfloat16* xt  = (__hip_bfloat16*)alloc((size_t)M * DIMc * 2);
  float* hb    = (float*)alloc((size_t)M * 2 * INNERc * 4);
  __hip_bfloat16* actb = (__hip_bfloat16*)alloc((size_t)M * INNERc * 2);
  (void)ws_size; (void)in_sizes; (void)n_in; (void)out_size;

  dim3 blk(256);

  // LN(cond) -> bf16
  ln_rows_bf16_k<<<M, blk, 0, stream>>>(cond, cnb, DCONDc);

  // weight transpose+cast
  const float* wc6[6] = {a1_gw, a1_bw, s1_w, a2_gw, a2_bw, s2_w};
  for (int i = 0; i < 6; ++i)
    transpose_cast_k<<<dim3(DIMc / 32, DCONDc / 32), blk, 0, stream>>>(
        wc6[i], Wc6t + (size_t)i * DIMc * DCONDc, DCONDc, DIMc);
  const float* wqkvg[4] = {wq, wk, wv, wg};
  for (int i = 0; i < 4; ++i)
    transpose_cast_k<<<dim3(DIMc / 32, DIMc / 32), blk, 0, stream>>>(
        wqkvg[i], Wqkvgt + (size_t)i * DIMc * DIMc, DIMc, DIMc);
  transpose_cast_k<<<dim3(DIMc / 32, DIMc / 32), blk, 0, stream>>>(wo, wot, DIMc, DIMc);
  transpose_cast_k<<<dim3(2 * INNERc / 32, DIMc / 32), blk, 0, stream>>>(tr_win, twint, DIMc, 2 * INNERc);
  transpose_cast_k<<<dim3(DIMc / 32, INNERc / 32), blk, 0, stream>>>(tr_wout, twoutt, INNERc, DIMc);

  concat_bias_k<<<(6 * DIMc + 255) / 256, blk, 0, stream>>>(a1_gb, s1_b, a2_gb, s2_b,
                                                            bq, bk, bv, bg, cb6, bqkvg);

  // fused 6-way cond projection: proj_c[M, 4608] (raw, bias added)
  gemm_bf16_k<4><<<dim3(6 * DIMc / 128, M / 128), blk, 0, stream>>>(
      cnb, Wc6t, proj_c, M, 6 * DIMc, DCONDc, cb6, nullptr, 0, nullptr, nullptr, 0);

  // adaLN1: xa (bf16) + xm (f32)
  adaln_apply_k<<<M, blk, 0, stream>>>(x, mask, proj_c + 0, proj_c + DIMc, 6 * DIMc, xa, xm);

  // fused QKVG projection: qkvg[M, 3072]
  gemm_bf16_k<4><<<dim3(4 * DIMc / 128, M / 128), blk, 0, stream>>>(
      xa, Wqkvgt, qkvg, M, 4 * DIMc, DIMc, bqkvg, nullptr, 0, nullptr, nullptr, 0);

  // per-head LN + RoPE on q and k segments
  lnrope_k<<<(M * Hc) / 4, blk, 0, stream>>>(qkvg);
  lnrope_k<<<(M * Hc) / 4, blk, 0, stream>>>(qkvg + DIMc);

  // windowed pair bias
  pair_bias_k<<<(Bc * Nc * NKc) / 4, blk, 0, stream>>>(pair_rep, wb_pair, biasw);

  // windowed attention (+fused sigmoid gate) -> obg bf16
  wattn_k<<<Bc * Hc * NWc, blk, 0, stream>>>(qkvg, biasw, pair_mask, obg);

  // x2 = ((obg @ wo + bo) * sig(s1raw) * mk^2 + xm) * mk
  gemm_bf16_k<2><<<dim3(DIMc / 64, M / 128), blk, 0, stream>>>(
      obg, wot, x2, M, DIMc, DIMc, bo, proj_c + 2 * DIMc, 6 * DIMc, xm, mask, 1);

  // adaLN2: xt (bf16)
  adaln_apply_k<<<M, blk, 0, stream>>>(x2, mask, proj_c + 3 * DIMc, proj_c + 4 * DIMc,
                                       6 * DIMc, xt, nullptr);

  // hb = xt @ tr_win
  gemm_bf16_k<4><<<dim3(2 * INNERc / 128, M / 128), blk, 0, stream>>>(
      xt, twint, hb, M, 2 * INNERc, DIMc, nullptr, nullptr, 0, nullptr, nullptr, 0);

  // actb = a * silu(g)
  silu_gate_k<<<(M * INNERc + 255) / 256, blk, 0, stream>>>(hb, actb, M * INNERc);

  // out = ((actb @ tr_wout) * mk * sig(s2raw) * mk^2 + x2) * mk^2
  gemm_bf16_k<2><<<dim3(DIMc / 64, M / 128), blk, 0, stream>>>(
      actb, twoutt, out, M, DIMc, INNERc, nullptr, proj_c + 5 * DIMc, 6 * DIMc, x2, mask, 2);
}

// Round 3
// 802.769 us; speedup vs baseline: 3.4746x; 1.2218x over previous
//
#include <hip/hip_runtime.h>
#include <hip/hip_bf16.h>
#include <math.h>

// Problem constants
#define Bc   2
#define Nc   512
#define Hc   12
#define DHc  64
#define DIMc 768
#define DPAIRc 128
#define DCONDc 512
#define INNERc 3072
#define NQc  32
#define NKc  128
#define NWc  (Nc / NQc)   // 16

typedef __attribute__((ext_vector_type(8))) short short8;
typedef __attribute__((ext_vector_type(4))) float floatx4;

// ---------------- helpers ----------------
__device__ inline float wave_sum(float v) {
#pragma unroll
  for (int off = 32; off > 0; off >>= 1) v += __shfl_xor(v, off, 64);
  return v;
}
__device__ inline float wave_max(float v) {
#pragma unroll
  for (int off = 32; off > 0; off >>= 1) v = fmaxf(v, __shfl_xor(v, off, 64));
  return v;
}
__device__ inline float block_sum(float v, float* red) {
  v = wave_sum(v);
  int wv = threadIdx.x >> 6, lane = threadIdx.x & 63;
  __syncthreads();
  if (lane == 0) red[wv] = v;
  __syncthreads();
  return red[0] + red[1] + red[2] + red[3];
}
__device__ inline float sigmoidf(float x) { return 1.0f / (1.0f + expf(-x)); }

// ---------------- LN over rows of cond -> bf16 ----------------
__global__ __launch_bounds__(256) void ln_rows_bf16_k(const float* __restrict__ in,
                                                      __hip_bfloat16* __restrict__ out, int C) {
  __shared__ float red[4];
  int row = blockIdx.x;
  const float* x = in + (size_t)row * C;
  float s = 0.f;
  for (int c = threadIdx.x; c < C; c += 256) s += x[c];
  float mean = block_sum(s, red) / C;
  float vs = 0.f;
  for (int c = threadIdx.x; c < C; c += 256) { float d = x[c] - mean; vs += d * d; }
  float var = block_sum(vs, red) / C;
  float r = rsqrtf(var + 1e-5f);
  for (int c = threadIdx.x; c < C; c += 256)
    out[(size_t)row * C + c] = __float2bfloat16((x[c] - mean) * r);
}

// ---------------- batched transpose+cast f32[K,N] -> bf16[N,K] ----------------
struct TP6 { const float* s0; const float* s1; const float* s2;
             const float* s3; const float* s4; const float* s5; };
__global__ __launch_bounds__(256) void transpose_cast_batch_k(TP6 p,
    __hip_bfloat16* __restrict__ dstBase, int K, int N) {
  __shared__ float tile[32][33];
  const float* srcs[6] = {p.s0, p.s1, p.s2, p.s3, p.s4, p.s5};
  const float* src = srcs[blockIdx.z];
  __hip_bfloat16* dst = dstBase + (size_t)blockIdx.z * K * N;
  int k0 = blockIdx.y * 32, n0 = blockIdx.x * 32;
  int t = threadIdx.x;
  int r = t >> 5, c = t & 31;
#pragma unroll
  for (int i = 0; i < 4; ++i) tile[r + i * 8][c] = src[(size_t)(k0 + r + i * 8) * N + n0 + c];
  __syncthreads();
#pragma unroll
  for (int i = 0; i < 4; ++i)
    dst[(size_t)(n0 + r + i * 8) * K + k0 + c] = __float2bfloat16(tile[c][r + i * 8]);
}

// ---------------- concat biases + wbT pack + colsum ----------------
__global__ __launch_bounds__(256) void concat_bias_k(
    const float* __restrict__ a1_gb, const float* __restrict__ s1_b,
    const float* __restrict__ a2_gb, const float* __restrict__ s2_b,
    const float* __restrict__ bq, const float* __restrict__ bk,
    const float* __restrict__ bv, const float* __restrict__ bg,
    const float* __restrict__ wb_pair,
    float* __restrict__ cb6, float* __restrict__ bqkvg,
    __hip_bfloat16* __restrict__ wbT, float* __restrict__ colsum) {
  int i = blockIdx.x * 256 + threadIdx.x;
  if (i < 6 * DIMc) {
    int seg = i / DIMc, o = i - seg * DIMc;
    float v = 0.f;
    if (seg == 0) v = a1_gb[o];
    else if (seg == 2) v = s1_b[o];
    else if (seg == 3) v = a2_gb[o];
    else if (seg == 5) v = s2_b[o];
    cb6[i] = v;
  }
  if (i < 4 * DIMc) {
    int seg = i / DIMc, o = i - seg * DIMc;
    bqkvg[i] = (seg == 0) ? bq[o] : (seg == 1) ? bk[o] : (seg == 2) ? bv[o] : bg[o];
  }
  if (i < 16 * DPAIRc) {
    int h = i >> 7, c = i & 127;
    wbT[i] = (h < Hc) ? __float2bfloat16(wb_pair[c * Hc + h]) : __float2bfloat16(0.f);
  }
  if (blockIdx.x == 0 && threadIdx.x < 16) {
    int h = threadIdx.x;
    float s = 0.f;
    if (h < Hc)
      for (int c = 0; c < DPAIRc; ++c)
        s += __bfloat162float(__float2bfloat16(wb_pair[c * Hc + h]));
    colsum[h] = s;
  }
}

// ---------------- bf16 MFMA GEMM: C[M,N] = A[M,K] @ Bt[N,K]^T + epilogue -------
template <int WNT>
__global__ __launch_bounds__(256) void gemm_bf16_k(
    const __hip_bfloat16* __restrict__ A, const __hip_bfloat16* __restrict__ Bt,
    float* __restrict__ C, int M, int N, int K,
    const float* __restrict__ bias,
    const float* __restrict__ ss, int ssst,
    const float* __restrict__ resid, const float* __restrict__ maskp, int mode) {
  constexpr int TN = 32 * WNT;
  constexpr int LD = 40;  // padded row (bf16 elems)
  __shared__ __hip_bfloat16 As[128 * LD];
  __shared__ __hip_bfloat16 Bs[TN * LD];
  int tid = threadIdx.x;
  int lane = tid & 63, wv = tid >> 6;
  int l16 = lane & 15, quad = lane >> 4;
  int m0 = blockIdx.y * 128, n0 = blockIdx.x * TN;
  int wm0 = (wv >> 1) * 64, wn0 = (wv & 1) * (16 * WNT);

  floatx4 acc[4][WNT];
#pragma unroll
  for (int mi = 0; mi < 4; ++mi)
#pragma unroll
    for (int nj = 0; nj < WNT; ++nj) acc[mi][nj] = (floatx4){0.f, 0.f, 0.f, 0.f};

  for (int k0 = 0; k0 < K; k0 += 32) {
#pragma unroll
    for (int e = tid; e < 512; e += 256) {
      int row = e >> 2, kc = (e & 3) * 8;
      *(uint4*)(void*)&As[row * LD + kc] =
          *(const uint4*)(const void*)&A[(size_t)(m0 + row) * K + k0 + kc];
    }
#pragma unroll
    for (int e = tid; e < TN * 4; e += 256) {
      int row = e >> 2, kc = (e & 3) * 8;
      *(uint4*)(void*)&Bs[row * LD + kc] =
          *(const uint4*)(const void*)&Bt[(size_t)(n0 + row) * K + k0 + kc];
    }
    __syncthreads();
    short8 a[4], b[WNT];
#pragma unroll
    for (int mi = 0; mi < 4; ++mi)
      a[mi] = *(const short8*)(const void*)&As[(wm0 + mi * 16 + l16) * LD + quad * 8];
#pragma unroll
    for (int nj = 0; nj < WNT; ++nj)
      b[nj] = *(const short8*)(const void*)&Bs[(wn0 + nj * 16 + l16) * LD + quad * 8];
#pragma unroll
    for (int mi = 0; mi < 4; ++mi)
#pragma unroll
      for (int nj = 0; nj < WNT; ++nj)
        acc[mi][nj] = __builtin_amdgcn_mfma_f32_16x16x32_bf16(a[mi], b[nj], acc[mi][nj], 0, 0, 0);
    __syncthreads();
  }

#pragma unroll
  for (int mi = 0; mi < 4; ++mi) {
#pragma unroll
    for (int nj = 0; nj < WNT; ++nj) {
      int ncol = n0 + wn0 + nj * 16 + l16;
      float bb = bias ? bias[ncol] : 0.f;
#pragma unroll
      for (int r = 0; r < 4; ++r) {
        int m = m0 + wm0 + mi * 16 + quad * 4 + r;
        float v = acc[mi][nj][r] + bb;
        if (mode == 1) {
          float mk = maskp[m];
          v *= sigmoidf(ss[(size_t)m * ssst + ncol]) * mk * mk;
          v = (v + resid[(size_t)m * N + ncol]) * mk;
        } else if (mode == 2) {
          float mk = maskp[m];
          v = v * mk * sigmoidf(ss[(size_t)m * ssst + ncol]) * mk * mk;
          v = (v + resid[(size_t)m * N + ncol]) * mk * mk;
        }
        C[(size_t)m * N + ncol] = v;
      }
    }
  }
}

// ---------------- adaLN apply (raw proj inputs, sigmoid fused) ----------------
__global__ __launch_bounds__(256) void adaln_apply_k(
    const float* __restrict__ xin, const float* __restrict__ maskp,
    const float* __restrict__ graw, const float* __restrict__ braw, int ssst,
    __hip_bfloat16* __restrict__ xa, float* __restrict__ xm) {
  __shared__ float red[4];
  int row = blockIdx.x;
  float mk = maskp[row];
  const float* xr = xin + (size_t)row * DIMc;
  float vals[3];
  float s = 0.f;
#pragma unroll
  for (int it = 0; it < 3; ++it) {
    int c = threadIdx.x + it * 256;
    float v = xr[c] * mk;
    vals[it] = v;
    s += v;
  }
  float mean = block_sum(s, red) * (1.0f / DIMc);
  float vs = 0.f;
#pragma unroll
  for (int it = 0; it < 3; ++it) { float d = vals[it] - mean; vs += d * d; }
  float var = block_sum(vs, red) * (1.0f / DIMc);
  float r = rsqrtf(var + 1e-5f);
#pragma unroll
  for (int it = 0; it < 3; ++it) {
    int c = threadIdx.x + it * 256;
    size_t sidx = (size_t)row * ssst + c;
    if (xm) xm[(size_t)row * DIMc + c] = vals[it];
    float o = ((vals[it] - mean) * r * sigmoidf(graw[sidx]) + braw[sidx]) * mk;
    xa[(size_t)row * DIMc + c] = __float2bfloat16(o);
  }
}

// ---------------- per-head LN + RoPE (in place, stride 3072) ----------------
// grid.y=0 -> q segment, grid.y=1 -> k segment
__global__ __launch_bounds__(256) void lnrope_k(float* __restrict__ qkvg) {
  float* q = qkvg + blockIdx.y * DIMc;
  int rowid = blockIdx.x * 4 + (threadIdx.x >> 6);  // (b*Nc+n)*Hc + h
  int lane = threadIdx.x & 63;
  int bn = rowid / Hc;
  int h = rowid - bn * Hc;
  int n = bn & (Nc - 1);
  size_t base = (size_t)bn * (4 * DIMc) + h * DHc;
  float v = q[base + lane];
  float mean = wave_sum(v) * (1.0f / 64.0f);
  float d = v - mean;
  float var = wave_sum(d * d) * (1.0f / 64.0f);
  float vn = d * rsqrtf(var + 1e-5f);
  int i = lane >> 1;
  // 10000^(-2i/64) = exp2(-i * log2(10000)/32)
  float inv = exp2f(-(float)i * 0.415241011861f);
  float ang = (float)n * inv;
  float c = cosf(ang), s = sinf(ang);
  float partner = __shfl_xor(vn, 1, 64);
  float out = (lane & 1) ? (partner * s + vn * c) : (vn * c - partner * s);
  q[base + lane] = out;
}

// ---------------- windowed pair bias via MFMA + post-LN fixup ----------------
// bias_h(row) = rstd * (sum_c bf16(v_c)*bf16(wb_c_h) - mean * colsum_h)
__global__ __launch_bounds__(256) void pair_bias_mfma_k(
    const float* __restrict__ pr, const __hip_bfloat16* __restrict__ wbT,
    const float* __restrict__ colsum, float* __restrict__ biasw) {
  constexpr int LDR = 136;  // bf16 elems per row (128 + 8 pad)
  __shared__ __hip_bfloat16 rows[128 * LDR];
  __shared__ float meanS[128];
  __shared__ float rstdS[128];
  int bi = blockIdx.x;           // b*512 + i
  int i = bi & (Nc - 1), b = bi >> 9;
  int w = i >> 5, qi = i & 31;
  int j0 = w * NQc - 48;
  int t = threadIdx.x;
  int sub = t >> 5;              // row-group within step (0..7)
  int c4 = t & 31;               // float4 index within row
  const float* prb = pr + (size_t)bi * (Nc * DPAIRc);
#pragma unroll
  for (int step = 0; step < 16; ++step) {
    int row = step * 8 + sub;
    int jc = min(max(j0 + row, 0), Nc - 1);
    float4 v = *(const float4*)(prb + (size_t)jc * DPAIRc + c4 * 4);
    union { __hip_bfloat16 h[4]; uint2 u; } pk;
    pk.h[0] = __float2bfloat16(v.x); pk.h[1] = __float2bfloat16(v.y);
    pk.h[2] = __float2bfloat16(v.z); pk.h[3] = __float2bfloat16(v.w);
    *(uint2*)(void*)&rows[row * LDR + c4 * 4] = pk.u;
    float s = v.x + v.y + v.z + v.w;
    float s2 = v.x * v.x + v.y * v.y + v.z * v.z + v.w * v.w;
#pragma unroll
    for (int off = 16; off > 0; off >>= 1) {
      s += __shfl_xor(s, off, 64);
      s2 += __shfl_xor(s2, off, 64);
    }
    if (c4 == 0) {
      float mean = s * (1.0f / 128.0f);
      float var = s2 * (1.0f / 128.0f) - mean * mean;
      meanS[row] = mean;
      rstdS[row] = rsqrtf(var + 1e-5f);
    }
  }
  __syncthreads();
  int lane = t & 63, wv = t >> 6;
  int l16 = lane & 15, quad = lane >> 4;
  short8 bfrag[4];
#pragma unroll
  for (int ks = 0; ks < 4; ++ks)
    bfrag[ks] = *(const short8*)(const void*)&wbT[l16 * 128 + ks * 32 + quad * 8];
  float cs = colsum[l16];
#pragma unroll
  for (int mt = 0; mt < 2; ++mt) {
    int mtile = wv * 2 + mt;
    floatx4 acc = (floatx4){0.f, 0.f, 0.f, 0.f};
#pragma unroll
    for (int ks = 0; ks < 4; ++ks) {
      short8 a = *(const short8*)(const void*)&rows[(mtile * 16 + l16) * LDR + ks * 32 + quad * 8];
      acc = __builtin_amdgcn_mfma_f32_16x16x32_bf16(a, bfrag[ks], acc, 0, 0, 0);
    }
    if (l16 < Hc) {
      int m0r = mtile * 16 + quad * 4;
      float4 ov;
      float* po = &ov.x;
#pragma unroll
      for (int r = 0; r < 4; ++r) {
        int m = m0r + r;
        po[r] = rstdS[m] * (acc[r] - meanS[m] * cs);
      }
      *(float4*)&biasw[((((size_t)(b * Hc + l16)) * NWc + w) * NQc + qi) * NKc + m0r] = ov;
    }
  }
}

// ---------------- windowed attention (packed QKVG, fused output gate) --------
__global__ __launch_bounds__(256) void wattn_k(
    const float* __restrict__ qkvg, const float* __restrict__ biasw,
    const float* __restrict__ pair_mask, __hip_bfloat16* __restrict__ o) {
  __shared__ float qs[32][68];
  __shared__ float ks[128][68];
  __shared__ float vs[128][68];
  __shared__ float sc[32][132];
  const int QS = 4 * DIMc;  // 3072
  int blk = blockIdx.x;  // (b*Hc + h)*NWc + w
  int w = blk & (NWc - 1);
  int bh = blk >> 4;
  int h = bh % Hc;
  int b = bh / Hc;
  int t = threadIdx.x;
  // stage q: 32 rows x 16 float4
  for (int e = t; e < 512; e += 256) {
    int qrow = e >> 4, c4 = e & 15;
    *(float4*)&qs[qrow][c4 * 4] =
        *(const float4*)&qkvg[(size_t)(b * Nc + w * NQc + qrow) * QS + h * DHc + c4 * 4];
  }
  // stage k,v: 128 rows x 16 float4 each
  for (int e = t; e < 2048; e += 256) {
    int kk = e >> 4, c4 = e & 15;
    int j = w * NQc - 48 + kk;
    int jc = min(max(j, 0), Nc - 1);
    size_t src = (size_t)(b * Nc + jc) * QS + h * DHc + c4 * 4;
    *(float4*)&ks[kk][c4 * 4] = *(const float4*)&qkvg[src + DIMc];
    *(float4*)&vs[kk][c4 * 4] = *(const float4*)&qkvg[src + 2 * DIMc];
  }
  __syncthreads();
  int qi = t >> 3;
  int kbase = (t & 7) * 16;
  const float* bwp = biasw + (((size_t)blk) * NQc + qi) * NKc;
  // q row in registers
  float4 qreg[16];
#pragma unroll
  for (int c = 0; c < 16; ++c) qreg[c] = *(float4*)&qs[qi][c * 4];
  float scf[16];
#pragma unroll
  for (int e = 0; e < 16; ++e) {
    int kk = kbase + e;
    float acc = 0.f;
#pragma unroll
    for (int c = 0; c < 16; ++c) {
      float4 kv = *(float4*)&ks[kk][c * 4];
      acc += qreg[c].x * kv.x + qreg[c].y * kv.y + qreg[c].z * kv.z + qreg[c].w * kv.w;
    }
    scf[e] = acc;
  }
#pragma unroll
  for (int e4 = 0; e4 < 4; ++e4) {
    float4 bw4 = *(const float4*)&bwp[kbase + e4 * 4];
    const float* pbw = &bw4.x;
    float4 sv4;
    float* ps = &sv4.x;
#pragma unroll
    for (int u = 0; u < 4; ++u) {
      int e = e4 * 4 + u;
      int kk = kbase + e;
      int j = w * NQc - 48 + kk;
      bool valid = (j >= 0) && (j < Nc);
      int jc = min(max(j, 0), Nc - 1);
      float pm = pair_mask[((size_t)(b * Nc + w * NQc + qi)) * Nc + jc];
      bool ok = valid && (pm > 0.f);
      ps[u] = ok ? (scf[e] * 0.125f + pbw[u]) : -1e9f;
    }
    *(float4*)&sc[qi][kbase + e4 * 4] = sv4;
  }
  __syncthreads();
  int lane = t & 63, wv = t >> 6;
#pragma unroll
  for (int rr = 0; rr < 8; ++rr) {
    int qq = wv * 8 + rr;
    float v0 = sc[qq][lane], v1 = sc[qq][lane + 64];
    float mx = wave_max(fmaxf(v0, v1));
    float e0 = expf(v0 - mx), e1 = expf(v1 - mx);
    float inv = 1.0f / wave_sum(e0 + e1);
    sc[qq][lane] = e0 * inv;
    sc[qq][lane + 64] = e1 * inv;
  }
  __syncthreads();
  int dbase = (t & 7) * 8;
  float accv[8] = {};
  for (int kk = 0; kk < 128; ++kk) {
    float a = sc[qi][kk];
    float4 v0 = *(float4*)&vs[kk][dbase];
    float4 v1 = *(float4*)&vs[kk][dbase + 4];
    accv[0] += a * v0.x; accv[1] += a * v0.y; accv[2] += a * v0.z; accv[3] += a * v0.w;
    accv[4] += a * v1.x; accv[5] += a * v1.y; accv[6] += a * v1.z; accv[7] += a * v1.w;
  }
  size_t mrow = (size_t)(b * Nc + w * NQc + qi);
  float4 g0 = *(const float4*)&qkvg[mrow * QS + 3 * DIMc + h * DHc + dbase];
  float4 g1 = *(const float4*)&qkvg[mrow * QS + 3 * DIMc + h * DHc + dbase + 4];
  union { __hip_bfloat16 hh[8]; uint4 u; } ok8;
  ok8.hh[0] = __float2bfloat16(accv[0] * sigmoidf(g0.x));
  ok8.hh[1] = __float2bfloat16(accv[1] * sigmoidf(g0.y));
  ok8.hh[2] = __float2bfloat16(accv[2] * sigmoidf(g0.z));
  ok8.hh[3] = __float2bfloat16(accv[3] * sigmoidf(g0.w));
  ok8.hh[4] = __float2bfloat16(accv[4] * sigmoidf(g1.x));
  ok8.hh[5] = __float2bfloat16(accv[5] * sigmoidf(g1.y));
  ok8.hh[6] = __float2bfloat16(accv[6] * sigmoidf(g1.z));
  ok8.hh[7] = __float2bfloat16(accv[7] * sigmoidf(g1.w));
  *(uint4*)(void*)&o[mrow * DIMc + h * DHc + dbase] = ok8.u;
}

// ---------------- silu gate -> bf16 ----------------
__global__ __launch_bounds__(256) void silu_gate_k(const float* __restrict__ h,
                                                   __hip_bfloat16* __restrict__ act, int total) {
  int i = blockIdx.x * 256 + threadIdx.x;
  if (i < total) {
    int m = i / INNERc, j = i - m * INNERc;
    float a = h[(size_t)m * (2 * INNERc) + j];
    float g = h[(size_t)m * (2 * INNERc) + INNERc + j];
    act[i] = __float2bfloat16(a * g * sigmoidf(g));
  }
}

extern "C" void kernel_launch(void* const* d_in, const int* in_sizes, int n_in,
                              void* d_out, int out_size, void* d_ws, size_t ws_size,
                              hipStream_t stream) {
  const float* x        = (const float*)d_in[0];
  const float* pair_rep = (const float*)d_in[1];
  const float* cond     = (const float*)d_in[2];
  const float* mask     = (const float*)d_in[3];
  const float* pair_mask= (const float*)d_in[4];
  const float* a1_gw    = (const float*)d_in[5];
  const float* a1_gb    = (const float*)d_in[6];
  const float* a1_bw    = (const float*)d_in[7];
  const float* wq       = (const float*)d_in[8];
  const float* bq       = (const float*)d_in[9];
  const float* wk       = (const float*)d_in[10];
  const float* bk       = (const float*)d_in[11];
  const float* wv       = (const float*)d_in[12];
  const float* bv       = (const float*)d_in[13];
  const float* wg       = (const float*)d_in[14];
  const float* bg       = (const float*)d_in[15];
  const float* wb_pair  = (const float*)d_in[16];
  const float* wo       = (const float*)d_in[17];
  const float* bo       = (const float*)d_in[18];
  const float* s1_w     = (const float*)d_in[19];
  const float* s1_b     = (const float*)d_in[20];
  const float* a2_gw    = (const float*)d_in[21];
  const float* a2_gb    = (const float*)d_in[22];
  const float* a2_bw    = (const float*)d_in[23];
  const float* tr_win   = (const float*)d_in[24];
  const float* tr_wout  = (const float*)d_in[25];
  const float* s2_w     = (const float*)d_in[26];
  const float* s2_b     = (const float*)d_in[27];
  float* out = (float*)d_out;

  const int M = Bc * Nc;  // 1024
  char* wsb = (char*)d_ws;
  size_t off = 0;
  auto alloc = [&](size_t bytes) { void* p = wsb + off; off += (bytes + 255) & ~(size_t)255; return p; };

  __hip_bfloat16* cnb     = (__hip_bfloat16*)alloc((size_t)M * DCONDc * 2);
  __hip_bfloat16* Wc6t    = (__hip_bfloat16*)alloc((size_t)6 * DIMc * DCONDc * 2);
  __hip_bfloat16* Wqkvg5t = (__hip_bfloat16*)alloc((size_t)5 * DIMc * DIMc * 2);
  __hip_bfloat16* twint   = (__hip_bfloat16*)alloc((size_t)2 * INNERc * DIMc * 2);
  __hip_bfloat16* twoutt  = (__hip_bfloat16*)alloc((size_t)DIMc * INNERc * 2);
  float* cb6    = (float*)alloc((size_t)6 * DIMc * 4);
  float* bqkvg  = (float*)alloc((size_t)4 * DIMc * 4);
  __hip_bfloat16* wbT = (__hip_bfloat16*)alloc((size_t)16 * DPAIRc * 2);
  float* colsum = (float*)alloc(16 * 4);
  float* proj_c = (float*)alloc((size_t)M * 6 * DIMc * 4);
  float* xm     = (float*)alloc((size_t)M * DIMc * 4);
  __hip_bfloat16* xa = (__hip_bfloat16*)alloc((size_t)M * DIMc * 2);
  float* qkvg   = (float*)alloc((size_t)M * 4 * DIMc * 4);
  float* biasw  = (float*)alloc((size_t)Bc * Hc * NWc * NQc * NKc * 4);
  __hip_bfloat16* obg = (__hip_bfloat16*)alloc((size_t)M * DIMc * 2);
  float* x2     = (float*)alloc((size_t)M * DIMc * 4);
  __hip_bfloat16* xt = (__hip_bfloat16*)alloc((size_t)M * DIMc * 2);
  float* hb     = (float*)alloc((size_t)M * 2 * INNERc * 4);
  __hip_bfloat16* actb = (__hip_bfloat16*)alloc((size_t)M * INNERc * 2);
  __hip_bfloat16* wot = Wqkvg5t + (size_t)4 * DIMc * DIMc;
  (void)ws_size; (void)in_sizes; (void)n_in; (void)out_size;

  dim3 blk(256);

  // LN(cond) -> bf16
  ln_rows_bf16_k<<<M, blk, 0, stream>>>(cond, cnb, DCONDc);

  // weight transposes (batched)
  transpose_cast_batch_k<<<dim3(DIMc / 32, DCONDc / 32, 6), blk, 0, stream>>>(
      TP6{a1_gw, a1_bw, s1_w, a2_gw, a2_bw, s2_w}, Wc6t, DCONDc, DIMc);
  transpose_cast_batch_k<<<dim3(DIMc / 32, DIMc / 32, 5), blk, 0, stream>>>(
      TP6{wq, wk, wv, wg, wo, wo}, Wqkvg5t, DIMc, DIMc);
  transpose_cast_batch_k<<<dim3(2 * INNERc / 32, DIMc / 32, 1), blk, 0, stream>>>(
      TP6{tr_win, tr_win, tr_win, tr_win, tr_win, tr_win}, twint, DIMc, 2 * INNERc);
  transpose_cast_batch_k<<<dim3(DIMc / 32, INNERc / 32, 1), blk, 0, stream>>>(
      TP6{tr_wout, tr_wout, tr_wout, tr_wout, tr_wout, tr_wout}, twoutt, INNERc, DIMc);

  concat_bias_k<<<(6 * DIMc + 255) / 256, blk, 0, stream>>>(
      a1_gb, s1_b, a2_gb, s2_b, bq, bk, bv, bg, wb_pair, cb6, bqkvg, wbT, colsum);

  // fused 6-way cond projection: proj_c[M, 4608] (raw, bias added)
  gemm_bf16_k<4><<<dim3(6 * DIMc / 128, M / 128), blk, 0, stream>>>(
      cnb, Wc6t, proj_c, M, 6 * DIMc, DCONDc, cb6, nullptr, 0, nullptr, nullptr, 0);

  // adaLN1: xa (bf16) + xm (f32)
  adaln_apply_k<<<M, blk, 0, stream>>>(x, mask, proj_c + 0, proj_c + DIMc, 6 * DIMc, xa, xm);

  // fused QKVG projection: qkvg[M, 3072]
  gemm_bf16_k<4><<<dim3(4 * DIMc / 128, M / 128), blk, 0, stream>>>(
      xa, Wqkvg5t, qkvg, M, 4 * DIMc, DIMc, bqkvg, nullptr, 0, nullptr, nullptr, 0);

  // per-head LN + RoPE on q and k segments (one launch)
  lnrope_k<<<dim3((M * Hc) / 4, 2), blk, 0, stream>>>(qkvg);

  // windowed pair bias (MFMA)
  pair_bias_mfma_k<<<Bc * Nc, blk, 0, stream>>>(pair_rep, wbT, colsum, biasw);

  // windowed attention (+fused sigmoid gate) -> obg bf16
  wattn_k<<<Bc * Hc * NWc, blk, 0, stream>>>(qkvg, biasw, pair_mask, obg);

  // x2 = ((obg @ wo + bo) * sig(s1raw) * mk^2 + xm) * mk
  gemm_bf16_k<1><<<dim3(DIMc / 32, M / 128), blk, 0, stream>>>(
      obg, wot, x2, M, DIMc, DIMc, bo, proj_c + 2 * DIMc, 6 * DIMc, xm, mask, 1);

  // adaLN2: xt (bf16)
  adaln_apply_k<<<M, blk, 0, stream>>>(x2, mask, proj_c + 3 * DIMc, proj_c + 4 * DIMc,
                                       6 * DIMc, xt, nullptr);

  // hb = xt @ tr_win
  gemm_bf16_k<4><<<dim3(2 * INNERc / 128, M / 128), blk, 0, stream>>>(
      xt, twint, hb, M, 2 * INNERc, DIMc, nullptr, nullptr, 0, nullptr, nullptr, 0);

  // actb = a * silu(g)
  silu_gate_k<<<(M * INNERc + 255) / 256, blk, 0, stream>>>(hb, actb, M * INNERc);

  // out = ((actb @ tr_wout) * mk * sig(s2raw) * mk^2 + x2) * mk^2
  gemm_bf16_k<1><<<dim3(DIMc / 32, M / 128), blk, 0, stream>>>(
      actb, twoutt, out, M, DIMc, INNERc, nullptr, proj_c + 5 * DIMc, 6 * DIMc, x2, mask, 2);
}

// Round 4
// 683.006 us; speedup vs baseline: 4.0839x; 1.1753x over previous
//
#include <hip/hip_runtime.h>
#include <hip/hip_bf16.h>
#include <math.h>

// Problem constants
#define Bc   2
#define Nc   512
#define Hc   12
#define DHc  64
#define DIMc 768
#define DPAIRc 128
#define DCONDc 512
#define INNERc 3072
#define NQc  32
#define NKc  128
#define NWc  (Nc / NQc)   // 16

typedef __attribute__((ext_vector_type(8))) short short8;
typedef __attribute__((ext_vector_type(4))) float floatx4;

// ---------------- helpers ----------------
__device__ inline float wave_sum(float v) {
#pragma unroll
  for (int off = 32; off > 0; off >>= 1) v += __shfl_xor(v, off, 64);
  return v;
}
__device__ inline float wave_max(float v) {
#pragma unroll
  for (int off = 32; off > 0; off >>= 1) v = fmaxf(v, __shfl_xor(v, off, 64));
  return v;
}
__device__ inline float block_sum(float v, float* red) {
  v = wave_sum(v);
  int wv = threadIdx.x >> 6, lane = threadIdx.x & 63;
  __syncthreads();
  if (lane == 0) red[wv] = v;
  __syncthreads();
  return red[0] + red[1] + red[2] + red[3];
}
__device__ inline float sigmoidf(float x) { return 1.0f / (1.0f + expf(-x)); }

// ---------------- LN over rows of cond -> bf16 ----------------
__global__ __launch_bounds__(256) void ln_rows_bf16_k(const float* __restrict__ in,
                                                      __hip_bfloat16* __restrict__ out, int C) {
  __shared__ float red[4];
  int row = blockIdx.x;
  const float* x = in + (size_t)row * C;
  float s = 0.f;
  for (int c = threadIdx.x; c < C; c += 256) s += x[c];
  float mean = block_sum(s, red) / C;
  float vs = 0.f;
  for (int c = threadIdx.x; c < C; c += 256) { float d = x[c] - mean; vs += d * d; }
  float var = block_sum(vs, red) / C;
  float r = rsqrtf(var + 1e-5f);
  for (int c = threadIdx.x; c < C; c += 256)
    out[(size_t)row * C + c] = __float2bfloat16((x[c] - mean) * r);
}

// ---------------- batched transpose+cast f32[K,N] -> bf16[N,K] ----------------
struct TP6 { const float* s0; const float* s1; const float* s2;
             const float* s3; const float* s4; const float* s5; };
__global__ __launch_bounds__(256) void transpose_cast_batch_k(TP6 p,
    __hip_bfloat16* __restrict__ dstBase, int K, int N) {
  __shared__ float tile[32][33];
  const float* srcs[6] = {p.s0, p.s1, p.s2, p.s3, p.s4, p.s5};
  const float* src = srcs[blockIdx.z];
  __hip_bfloat16* dst = dstBase + (size_t)blockIdx.z * K * N;
  int k0 = blockIdx.y * 32, n0 = blockIdx.x * 32;
  int t = threadIdx.x;
  int r = t >> 5, c = t & 31;
#pragma unroll
  for (int i = 0; i < 4; ++i) tile[r + i * 8][c] = src[(size_t)(k0 + r + i * 8) * N + n0 + c];
  __syncthreads();
#pragma unroll
  for (int i = 0; i < 4; ++i)
    dst[(size_t)(n0 + r + i * 8) * K + k0 + c] = __float2bfloat16(tile[c][r + i * 8]);
}

// ---------------- concat biases + wbT pack + colsum ----------------
__global__ __launch_bounds__(256) void concat_bias_k(
    const float* __restrict__ a1_gb, const float* __restrict__ s1_b,
    const float* __restrict__ a2_gb, const float* __restrict__ s2_b,
    const float* __restrict__ bq, const float* __restrict__ bk,
    const float* __restrict__ bv, const float* __restrict__ bg,
    const float* __restrict__ wb_pair,
    float* __restrict__ cb6, float* __restrict__ bqkvg,
    __hip_bfloat16* __restrict__ wbT, float* __restrict__ colsum) {
  int i = blockIdx.x * 256 + threadIdx.x;
  if (i < 6 * DIMc) {
    int seg = i / DIMc, o = i - seg * DIMc;
    float v = 0.f;
    if (seg == 0) v = a1_gb[o];
    else if (seg == 2) v = s1_b[o];
    else if (seg == 3) v = a2_gb[o];
    else if (seg == 5) v = s2_b[o];
    cb6[i] = v;
  }
  if (i < 4 * DIMc) {
    int seg = i / DIMc, o = i - seg * DIMc;
    bqkvg[i] = (seg == 0) ? bq[o] : (seg == 1) ? bk[o] : (seg == 2) ? bv[o] : bg[o];
  }
  if (i < 16 * DPAIRc) {
    int h = i >> 7, c = i & 127;
    wbT[i] = (h < Hc) ? __float2bfloat16(wb_pair[c * Hc + h]) : __float2bfloat16(0.f);
  }
  if (blockIdx.x == 0 && threadIdx.x < 16) {
    int h = threadIdx.x;
    float s = 0.f;
    if (h < Hc)
      for (int c = 0; c < DPAIRc; ++c)
        s += __bfloat162float(__float2bfloat16(wb_pair[c * Hc + h]));
    colsum[h] = s;
  }
}

// ---------------- bf16 MFMA GEMM: C[M,N] = A[M,K] @ Bt[N,K]^T + epilogue -------
template <int WNT>
__global__ __launch_bounds__(256) void gemm_bf16_k(
    const __hip_bfloat16* __restrict__ A, const __hip_bfloat16* __restrict__ Bt,
    float* __restrict__ C, int M, int N, int K,
    const float* __restrict__ bias,
    const float* __restrict__ ss, int ssst,
    const float* __restrict__ resid, const float* __restrict__ maskp, int mode) {
  constexpr int TN = 32 * WNT;
  constexpr int LD = 40;  // padded row (bf16 elems)
  __shared__ __hip_bfloat16 As[128 * LD];
  __shared__ __hip_bfloat16 Bs[TN * LD];
  int tid = threadIdx.x;
  int lane = tid & 63, wv = tid >> 6;
  int l16 = lane & 15, quad = lane >> 4;
  int m0 = blockIdx.y * 128, n0 = blockIdx.x * TN;
  int wm0 = (wv >> 1) * 64, wn0 = (wv & 1) * (16 * WNT);

  floatx4 acc[4][WNT];
#pragma unroll
  for (int mi = 0; mi < 4; ++mi)
#pragma unroll
    for (int nj = 0; nj < WNT; ++nj) acc[mi][nj] = (floatx4){0.f, 0.f, 0.f, 0.f};

  for (int k0 = 0; k0 < K; k0 += 32) {
#pragma unroll
    for (int e = tid; e < 512; e += 256) {
      int row = e >> 2, kc = (e & 3) * 8;
      *(uint4*)(void*)&As[row * LD + kc] =
          *(const uint4*)(const void*)&A[(size_t)(m0 + row) * K + k0 + kc];
    }
#pragma unroll
    for (int e = tid; e < TN * 4; e += 256) {
      int row = e >> 2, kc = (e & 3) * 8;
      *(uint4*)(void*)&Bs[row * LD + kc] =
          *(const uint4*)(const void*)&Bt[(size_t)(n0 + row) * K + k0 + kc];
    }
    __syncthreads();
    short8 a[4], b[WNT];
#pragma unroll
    for (int mi = 0; mi < 4; ++mi)
      a[mi] = *(const short8*)(const void*)&As[(wm0 + mi * 16 + l16) * LD + quad * 8];
#pragma unroll
    for (int nj = 0; nj < WNT; ++nj)
      b[nj] = *(const short8*)(const void*)&Bs[(wn0 + nj * 16 + l16) * LD + quad * 8];
#pragma unroll
    for (int mi = 0; mi < 4; ++mi)
#pragma unroll
      for (int nj = 0; nj < WNT; ++nj)
        acc[mi][nj] = __builtin_amdgcn_mfma_f32_16x16x32_bf16(a[mi], b[nj], acc[mi][nj], 0, 0, 0);
    __syncthreads();
  }

#pragma unroll
  for (int mi = 0; mi < 4; ++mi) {
#pragma unroll
    for (int nj = 0; nj < WNT; ++nj) {
      int ncol = n0 + wn0 + nj * 16 + l16;
      float bb = bias ? bias[ncol] : 0.f;
#pragma unroll
      for (int r = 0; r < 4; ++r) {
        int m = m0 + wm0 + mi * 16 + quad * 4 + r;
        float v = acc[mi][nj][r] + bb;
        if (mode == 1) {
          float mk = maskp[m];
          v *= sigmoidf(ss[(size_t)m * ssst + ncol]) * mk * mk;
          v = (v + resid[(size_t)m * N + ncol]) * mk;
        } else if (mode == 2) {
          float mk = maskp[m];
          v = v * mk * sigmoidf(ss[(size_t)m * ssst + ncol]) * mk * mk;
          v = (v + resid[(size_t)m * N + ncol]) * mk * mk;
        }
        C[(size_t)m * N + ncol] = v;
      }
    }
  }
}

// ---------------- adaLN apply (raw proj inputs, sigmoid fused) ----------------
__global__ __launch_bounds__(256) void adaln_apply_k(
    const float* __restrict__ xin, const float* __restrict__ maskp,
    const float* __restrict__ graw, const float* __restrict__ braw, int ssst,
    __hip_bfloat16* __restrict__ xa, float* __restrict__ xm) {
  __shared__ float red[4];
  int row = blockIdx.x;
  float mk = maskp[row];
  const float* xr = xin + (size_t)row * DIMc;
  float vals[3];
  float s = 0.f;
#pragma unroll
  for (int it = 0; it < 3; ++it) {
    int c = threadIdx.x + it * 256;
    float v = xr[c] * mk;
    vals[it] = v;
    s += v;
  }
  float mean = block_sum(s, red) * (1.0f / DIMc);
  float vs = 0.f;
#pragma unroll
  for (int it = 0; it < 3; ++it) { float d = vals[it] - mean; vs += d * d; }
  float var = block_sum(vs, red) * (1.0f / DIMc);
  float r = rsqrtf(var + 1e-5f);
#pragma unroll
  for (int it = 0; it < 3; ++it) {
    int c = threadIdx.x + it * 256;
    size_t sidx = (size_t)row * ssst + c;
    if (xm) xm[(size_t)row * DIMc + c] = vals[it];
    float o = ((vals[it] - mean) * r * sigmoidf(graw[sidx]) + braw[sidx]) * mk;
    xa[(size_t)row * DIMc + c] = __float2bfloat16(o);
  }
}

// ---------------- per-head LN + RoPE (in place, stride 3072) ----------------
__global__ __launch_bounds__(256) void lnrope_k(float* __restrict__ qkvg) {
  float* q = qkvg + blockIdx.y * DIMc;
  int rowid = blockIdx.x * 4 + (threadIdx.x >> 6);  // (b*Nc+n)*Hc + h
  int lane = threadIdx.x & 63;
  int bn = rowid / Hc;
  int h = rowid - bn * Hc;
  int n = bn & (Nc - 1);
  size_t base = (size_t)bn * (4 * DIMc) + h * DHc;
  float v = q[base + lane];
  float mean = wave_sum(v) * (1.0f / 64.0f);
  float d = v - mean;
  float var = wave_sum(d * d) * (1.0f / 64.0f);
  float vn = d * rsqrtf(var + 1e-5f);
  int i = lane >> 1;
  float inv = exp2f(-(float)i * 0.415241011861f);
  float ang = (float)n * inv;
  float c = cosf(ang), s = sinf(ang);
  float partner = __shfl_xor(vn, 1, 64);
  float out = (lane & 1) ? (partner * s + vn * c) : (vn * c - partner * s);
  q[base + lane] = out;
}

// ---------------- windowed pair bias via MFMA + post-LN fixup ----------------
__global__ __launch_bounds__(256) void pair_bias_mfma_k(
    const float* __restrict__ pr, const __hip_bfloat16* __restrict__ wbT,
    const float* __restrict__ colsum, float* __restrict__ biasw) {
  constexpr int LDR = 136;
  __shared__ __hip_bfloat16 rows[128 * LDR];
  __shared__ float meanS[128];
  __shared__ float rstdS[128];
  int bi = blockIdx.x;           // b*512 + i
  int i = bi & (Nc - 1), b = bi >> 9;
  int w = i >> 5, qi = i & 31;
  int j0 = w * NQc - 48;
  int t = threadIdx.x;
  int sub = t >> 5;
  int c4 = t & 31;
  const float* prb = pr + (size_t)bi * (Nc * DPAIRc);
#pragma unroll
  for (int step = 0; step < 16; ++step) {
    int row = step * 8 + sub;
    int jc = min(max(j0 + row, 0), Nc - 1);
    float4 v = *(const float4*)(prb + (size_t)jc * DPAIRc + c4 * 4);
    union { __hip_bfloat16 h[4]; uint2 u; } pk;
    pk.h[0] = __float2bfloat16(v.x); pk.h[1] = __float2bfloat16(v.y);
    pk.h[2] = __float2bfloat16(v.z); pk.h[3] = __float2bfloat16(v.w);
    *(uint2*)(void*)&rows[row * LDR + c4 * 4] = pk.u;
    float s = v.x + v.y + v.z + v.w;
    float s2 = v.x * v.x + v.y * v.y + v.z * v.z + v.w * v.w;
#pragma unroll
    for (int off = 16; off > 0; off >>= 1) {
      s += __shfl_xor(s, off, 64);
      s2 += __shfl_xor(s2, off, 64);
    }
    if (c4 == 0) {
      float mean = s * (1.0f / 128.0f);
      float var = s2 * (1.0f / 128.0f) - mean * mean;
      meanS[row] = mean;
      rstdS[row] = rsqrtf(var + 1e-5f);
    }
  }
  __syncthreads();
  int lane = t & 63, wv = t >> 6;
  int l16 = lane & 15, quad = lane >> 4;
  short8 bfrag[4];
#pragma unroll
  for (int ks = 0; ks < 4; ++ks)
    bfrag[ks] = *(const short8*)(const void*)&wbT[l16 * 128 + ks * 32 + quad * 8];
  float cs = colsum[l16];
#pragma unroll
  for (int mt = 0; mt < 2; ++mt) {
    int mtile = wv * 2 + mt;
    floatx4 acc = (floatx4){0.f, 0.f, 0.f, 0.f};
#pragma unroll
    for (int ks = 0; ks < 4; ++ks) {
      short8 a = *(const short8*)(const void*)&rows[(mtile * 16 + l16) * LDR + ks * 32 + quad * 8];
      acc = __builtin_amdgcn_mfma_f32_16x16x32_bf16(a, bfrag[ks], acc, 0, 0, 0);
    }
    if (l16 < Hc) {
      int m0r = mtile * 16 + quad * 4;
      float4 ov;
      float* po = &ov.x;
#pragma unroll
      for (int r = 0; r < 4; ++r) {
        int m = m0r + r;
        po[r] = rstdS[m] * (acc[r] - meanS[m] * cs);
      }
      *(float4*)&biasw[((((size_t)(b * Hc + l16)) * NWc + w) * NQc + qi) * NKc + m0r] = ov;
    }
  }
}

// ---------------- windowed attention v2: MFMA QK^T and PV, bf16 staging ------
__global__ __launch_bounds__(256) void wattn_k(
    const float* __restrict__ qkvg, const float* __restrict__ biasw,
    const float* __restrict__ pair_mask, __hip_bfloat16* __restrict__ o) {
  constexpr int LQ = 72;    // shorts per q/k row (64 + 8 pad)
  constexpr int LV = 136;   // shorts per vT row (128 keys + 8 pad)
  constexpr int LS = 132;   // floats per score row
  constexpr int LP = 136;   // shorts per P row
  __shared__ __hip_bfloat16 qs[32 * LQ];
  __shared__ __hip_bfloat16 ks[128 * LQ];
  __shared__ __hip_bfloat16 vT[64 * LV];
  __shared__ float sc[32 * LS];
  __shared__ __hip_bfloat16 scP[32 * LP];
  const int QS = 4 * DIMc;  // 3072
  int blk = blockIdx.x;     // (b*Hc + h)*NWc + w
  int w = blk & (NWc - 1);
  int bh = blk >> 4;
  int h = bh % Hc;
  int b = bh / Hc;
  int t = threadIdx.x;
  int j0 = w * NQc - 48;
  // stage q (bf16)
  for (int e = t; e < 512; e += 256) {
    int qrow = e >> 4, c4 = e & 15;
    float4 v = *(const float4*)&qkvg[(size_t)(b * Nc + w * NQc + qrow) * QS + h * DHc + c4 * 4];
    union { __hip_bfloat16 hh[4]; uint2 u; } pk;
    pk.hh[0] = __float2bfloat16(v.x); pk.hh[1] = __float2bfloat16(v.y);
    pk.hh[2] = __float2bfloat16(v.z); pk.hh[3] = __float2bfloat16(v.w);
    *(uint2*)(void*)&qs[qrow * LQ + c4 * 4] = pk.u;
  }
  // stage k (bf16 row-major) and v (bf16 transposed)
  for (int e = t; e < 2048; e += 256) {
    int kk = e >> 4, c4 = e & 15;
    int jc = min(max(j0 + kk, 0), Nc - 1);
    size_t src = (size_t)(b * Nc + jc) * QS + h * DHc + c4 * 4;
    float4 kv = *(const float4*)&qkvg[src + DIMc];
    float4 vv = *(const float4*)&qkvg[src + 2 * DIMc];
    union { __hip_bfloat16 hh[4]; uint2 u; } pk;
    pk.hh[0] = __float2bfloat16(kv.x); pk.hh[1] = __float2bfloat16(kv.y);
    pk.hh[2] = __float2bfloat16(kv.z); pk.hh[3] = __float2bfloat16(kv.w);
    *(uint2*)(void*)&ks[kk * LQ + c4 * 4] = pk.u;
    vT[(c4 * 4 + 0) * LV + kk] = __float2bfloat16(vv.x);
    vT[(c4 * 4 + 1) * LV + kk] = __float2bfloat16(vv.y);
    vT[(c4 * 4 + 2) * LV + kk] = __float2bfloat16(vv.z);
    vT[(c4 * 4 + 3) * LV + kk] = __float2bfloat16(vv.w);
  }
  // pre-fill score buffer with bias or -inf (mask/validity)
  for (int e = t; e < 4096; e += 256) {
    int qrow = e >> 7, key = e & 127;
    int j = j0 + key;
    bool valid = (j >= 0) && (j < Nc);
    int jc = min(max(j, 0), Nc - 1);
    float pm = pair_mask[((size_t)(b * Nc + w * NQc + qrow)) * Nc + jc];
    bool ok = valid && (pm > 0.f);
    sc[qrow * LS + key] = ok ? biasw[((size_t)blk * 32 + qrow) * 128 + key] : -1e30f;
  }
  __syncthreads();
  int lane = t & 63, wv = t >> 6;
  int l16 = lane & 15, quad = lane >> 4;
  // QK^T: wave wv handles keys [wv*32, wv*32+32), both m-tiles
  {
    short8 bfr[2][2];
#pragma unroll
    for (int nt = 0; nt < 2; ++nt)
#pragma unroll
      for (int k2 = 0; k2 < 2; ++k2)
        bfr[nt][k2] = *(const short8*)(const void*)&ks[(wv * 32 + nt * 16 + l16) * LQ + k2 * 32 + quad * 8];
#pragma unroll
    for (int mi = 0; mi < 2; ++mi) {
      short8 afr[2];
#pragma unroll
      for (int k2 = 0; k2 < 2; ++k2)
        afr[k2] = *(const short8*)(const void*)&qs[(mi * 16 + l16) * LQ + k2 * 32 + quad * 8];
#pragma unroll
      for (int nt = 0; nt < 2; ++nt) {
        floatx4 acc = (floatx4){0.f, 0.f, 0.f, 0.f};
        acc = __builtin_amdgcn_mfma_f32_16x16x32_bf16(afr[0], bfr[nt][0], acc, 0, 0, 0);
        acc = __builtin_amdgcn_mfma_f32_16x16x32_bf16(afr[1], bfr[nt][1], acc, 0, 0, 0);
        int key = wv * 32 + nt * 16 + l16;
#pragma unroll
        for (int r = 0; r < 4; ++r) {
          int m = mi * 16 + quad * 4 + r;
          float sv = sc[m * LS + key];
          if (sv > -1e29f) sc[m * LS + key] = sv + acc[r] * 0.125f;
        }
      }
    }
  }
  __syncthreads();
  // softmax: wave per 8 rows, write P as bf16
#pragma unroll
  for (int rr = 0; rr < 8; ++rr) {
    int qq = wv * 8 + rr;
    float v0 = sc[qq * LS + lane], v1 = sc[qq * LS + 64 + lane];
    float mx = wave_max(fmaxf(v0, v1));
    float e0 = expf(v0 - mx), e1 = expf(v1 - mx);
    float inv = 1.0f / wave_sum(e0 + e1);
    scP[qq * LP + lane] = __float2bfloat16(e0 * inv);
    scP[qq * LP + 64 + lane] = __float2bfloat16(e1 * inv);
  }
  __syncthreads();
  // PV: wave wv handles d-range [wv*16, wv*16+16), both m-tiles
  {
    short8 vb[4];
#pragma unroll
    for (int k4 = 0; k4 < 4; ++k4)
      vb[k4] = *(const short8*)(const void*)&vT[(wv * 16 + l16) * LV + k4 * 32 + quad * 8];
#pragma unroll
    for (int mi = 0; mi < 2; ++mi) {
      floatx4 acc = (floatx4){0.f, 0.f, 0.f, 0.f};
#pragma unroll
      for (int k4 = 0; k4 < 4; ++k4) {
        short8 pa = *(const short8*)(const void*)&scP[(mi * 16 + l16) * LP + k4 * 32 + quad * 8];
        acc = __builtin_amdgcn_mfma_f32_16x16x32_bf16(pa, vb[k4], acc, 0, 0, 0);
      }
      int d = wv * 16 + l16;
#pragma unroll
      for (int r = 0; r < 4; ++r) {
        int m = mi * 16 + quad * 4 + r;
        size_t mrow = (size_t)(b * Nc + w * NQc + m);
        float g = qkvg[mrow * QS + 3 * DIMc + h * DHc + d];
        o[mrow * DIMc + h * DHc + d] = __float2bfloat16(acc[r] * sigmoidf(g));
      }
    }
  }
}

// ---------------- silu gate -> bf16 ----------------
__global__ __launch_bounds__(256) void silu_gate_k(const float* __restrict__ h,
                                                   __hip_bfloat16* __restrict__ act, int total) {
  int i = blockIdx.x * 256 + threadIdx.x;
  if (i < total) {
    int m = i / INNERc, j = i - m * INNERc;
    float a = h[(size_t)m * (2 * INNERc) + j];
    float g = h[(size_t)m * (2 * INNERc) + INNERc + j];
    act[i] = __float2bfloat16(a * g * sigmoidf(g));
  }
}

extern "C" void kernel_launch(void* const* d_in, const int* in_sizes, int n_in,
                              void* d_out, int out_size, void* d_ws, size_t ws_size,
                              hipStream_t stream) {
  const float* x        = (const float*)d_in[0];
  const float* pair_rep = (const float*)d_in[1];
  const float* cond     = (const float*)d_in[2];
  const float* mask     = (const float*)d_in[3];
  const float* pair_mask= (const float*)d_in[4];
  const float* a1_gw    = (const float*)d_in[5];
  const float* a1_gb    = (const float*)d_in[6];
  const float* a1_bw    = (const float*)d_in[7];
  const float* wq       = (const float*)d_in[8];
  const float* bq       = (const float*)d_in[9];
  const float* wk       = (const float*)d_in[10];
  const float* bk       = (const float*)d_in[11];
  const float* wv       = (const float*)d_in[12];
  const float* bv       = (const float*)d_in[13];
  const float* wg       = (const float*)d_in[14];
  const float* bg       = (const float*)d_in[15];
  const float* wb_pair  = (const float*)d_in[16];
  const float* wo       = (const float*)d_in[17];
  const float* bo       = (const float*)d_in[18];
  const float* s1_w     = (const float*)d_in[19];
  const float* s1_b     = (const float*)d_in[20];
  const float* a2_gw    = (const float*)d_in[21];
  const float* a2_gb    = (const float*)d_in[22];
  const float* a2_bw    = (const float*)d_in[23];
  const float* tr_win   = (const float*)d_in[24];
  const float* tr_wout  = (const float*)d_in[25];
  const float* s2_w     = (const float*)d_in[26];
  const float* s2_b     = (const float*)d_in[27];
  float* out = (float*)d_out;

  const int M = Bc * Nc;  // 1024
  char* wsb = (char*)d_ws;
  size_t off = 0;
  auto alloc = [&](size_t bytes) { void* p = wsb + off; off += (bytes + 255) & ~(size_t)255; return p; };

  __hip_bfloat16* cnb     = (__hip_bfloat16*)alloc((size_t)M * DCONDc * 2);
  __hip_bfloat16* Wc6t    = (__hip_bfloat16*)alloc((size_t)6 * DIMc * DCONDc * 2);
  __hip_bfloat16* Wqkvg5t = (__hip_bfloat16*)alloc((size_t)5 * DIMc * DIMc * 2);
  __hip_bfloat16* twint   = (__hip_bfloat16*)alloc((size_t)2 * INNERc * DIMc * 2);
  __hip_bfloat16* twoutt  = (__hip_bfloat16*)alloc((size_t)DIMc * INNERc * 2);
  float* cb6    = (float*)alloc((size_t)6 * DIMc * 4);
  float* bqkvg  = (float*)alloc((size_t)4 * DIMc * 4);
  __hip_bfloat16* wbT = (__hip_bfloat16*)alloc((size_t)16 * DPAIRc * 2);
  float* colsum = (float*)alloc(16 * 4);
  float* proj_c = (float*)alloc((size_t)M * 6 * DIMc * 4);
  float* xm     = (float*)alloc((size_t)M * DIMc * 4);
  __hip_bfloat16* xa = (__hip_bfloat16*)alloc((size_t)M * DIMc * 2);
  float* qkvg   = (float*)alloc((size_t)M * 4 * DIMc * 4);
  float* biasw  = (float*)alloc((size_t)Bc * Hc * NWc * NQc * NKc * 4);
  __hip_bfloat16* obg = (__hip_bfloat16*)alloc((size_t)M * DIMc * 2);
  float* x2     = (float*)alloc((size_t)M * DIMc * 4);
  __hip_bfloat16* xt = (__hip_bfloat16*)alloc((size_t)M * DIMc * 2);
  float* hb     = (float*)alloc((size_t)M * 2 * INNERc * 4);
  __hip_bfloat16* actb = (__hip_bfloat16*)alloc((size_t)M * INNERc * 2);
  __hip_bfloat16* wot = Wqkvg5t + (size_t)4 * DIMc * DIMc;
  (void)ws_size; (void)in_sizes; (void)n_in; (void)out_size;

  dim3 blk(256);

  ln_rows_bf16_k<<<M, blk, 0, stream>>>(cond, cnb, DCONDc);

  transpose_cast_batch_k<<<dim3(DIMc / 32, DCONDc / 32, 6), blk, 0, stream>>>(
      TP6{a1_gw, a1_bw, s1_w, a2_gw, a2_bw, s2_w}, Wc6t, DCONDc, DIMc);
  transpose_cast_batch_k<<<dim3(DIMc / 32, DIMc / 32, 5), blk, 0, stream>>>(
      TP6{wq, wk, wv, wg, wo, wo}, Wqkvg5t, DIMc, DIMc);
  transpose_cast_batch_k<<<dim3(2 * INNERc / 32, DIMc / 32, 1), blk, 0, stream>>>(
      TP6{tr_win, tr_win, tr_win, tr_win, tr_win, tr_win}, twint, DIMc, 2 * INNERc);
  transpose_cast_batch_k<<<dim3(DIMc / 32, INNERc / 32, 1), blk, 0, stream>>>(
      TP6{tr_wout, tr_wout, tr_wout, tr_wout, tr_wout, tr_wout}, twoutt, INNERc, DIMc);

  concat_bias_k<<<(6 * DIMc + 255) / 256, blk, 0, stream>>>(
      a1_gb, s1_b, a2_gb, s2_b, bq, bk, bv, bg, wb_pair, cb6, bqkvg, wbT, colsum);

  gemm_bf16_k<4><<<dim3(6 * DIMc / 128, M / 128), blk, 0, stream>>>(
      cnb, Wc6t, proj_c, M, 6 * DIMc, DCONDc, cb6, nullptr, 0, nullptr, nullptr, 0);

  adaln_apply_k<<<M, blk, 0, stream>>>(x, mask, proj_c + 0, proj_c + DIMc, 6 * DIMc, xa, xm);

  gemm_bf16_k<4><<<dim3(4 * DIMc / 128, M / 128), blk, 0, stream>>>(
      xa, Wqkvg5t, qkvg, M, 4 * DIMc, DIMc, bqkvg, nullptr, 0, nullptr, nullptr, 0);

  lnrope_k<<<dim3((M * Hc) / 4, 2), blk, 0, stream>>>(qkvg);

  pair_bias_mfma_k<<<Bc * Nc, blk, 0, stream>>>(pair_rep, wbT, colsum, biasw);

  wattn_k<<<Bc * Hc * NWc, blk, 0, stream>>>(qkvg, biasw, pair_mask, obg);

  gemm_bf16_k<1><<<dim3(DIMc / 32, M / 128), blk, 0, stream>>>(
      obg, wot, x2, M, DIMc, DIMc, bo, proj_c + 2 * DIMc, 6 * DIMc, xm, mask, 1);

  adaln_apply_k<<<M, blk, 0, stream>>>(x2, mask, proj_c + 3 * DIMc, proj_c + 4 * DIMc,
                                       6 * DIMc, xt, nullptr);

  gemm_bf16_k<4><<<dim3(2 * INNERc / 128, M / 128), blk, 0, stream>>>(
      xt, twint, hb, M, 2 * INNERc, DIMc, nullptr, nullptr, 0, nullptr, nullptr, 0);

  silu_gate_k<<<(M * INNERc + 255) / 256, blk, 0, stream>>>(hb, actb, M * INNERc);

  gemm_bf16_k<1><<<dim3(DIMc / 32, M / 128), blk, 0, stream>>>(
      actb, twoutt, out, M, DIMc, INNERc, nullptr, proj_c + 5 * DIMc, 6 * DIMc, x2, mask, 2);
}